// Round 7
// baseline (387.199 us; speedup 1.0000x reference)
//
#include <hip/hip_runtime.h>
#include <hip/hip_bf16.h>
#include <cstdint>

#define SEQ     2048
#define NHID    2048
#define NLAT    512
#define NHEAD   16
#define DHEAD   128
#define NBATCH  2
#define NROWS   (NBATCH*SEQ)   // 4096

typedef unsigned short u16;
typedef __attribute__((ext_vector_type(8))) short short8;
typedef __attribute__((ext_vector_type(4))) float f32x4;

#define MFMA16 __builtin_amdgcn_mfma_f32_16x16x32_bf16

// 1/sqrt(128) * log2(e): folded into the Q projection so attn softmax is a raw exp2
#define QSCALE 0.12751743f

#if __has_builtin(__builtin_amdgcn_exp2f)
#define EXP2(x) __builtin_amdgcn_exp2f(x)
#else
#define EXP2(x) __expf((x) * 0.6931471805599453f)
#endif

__device__ __forceinline__ u16 f2b(float f) {
    uint32_t u = __float_as_uint(f);
    uint32_t r = (u + 0x7fffu + ((u >> 16) & 1u)) >> 16;   // RNE
    return (u16)r;
}

// HW packed f32->bf16 (RNE): lo = bf16(a), hi = bf16(b)
__device__ __forceinline__ uint32_t cvt_pk_bf16(float a, float b) {
    uint32_t r;
    asm("v_cvt_pk_bf16_f32 %0, %1, %2" : "=v"(r) : "v"(a), "v"(b));
    return r;
}

__device__ __forceinline__ void async16(const u16* g, u16* l) {
    __builtin_amdgcn_global_load_lds(
        (const __attribute__((address_space(1))) unsigned int*)g,
        (__attribute__((address_space(3))) unsigned int*)l, 16, 0, 0);
}

// Stage a tile of [rows][cols] bf16 (cols = chunks-of-8 * 8) from global (row
// stride strideE elems) into LDS, 16B per lane, wave-uniform LDS base.
// Logical chunk LC of row r is stored at slot LC ^ ((r >> xshift) & xmask).
__device__ __forceinline__ void stage_lds(const u16* __restrict__ src, size_t strideE,
                                          u16* lds, int wave, int lane,
                                          int log2cpr, int xmask, int xshift,
                                          int reps, int nlanes) {
    const int cmask = (1 << log2cpr) - 1;
    for (int rep = 0; rep < reps; ++rep) {
        int cbase = rep * nlanes + wave * 64;     // wave-uniform
        int ci = cbase + lane;
        int row = ci >> log2cpr;
        int sc = ci & cmask;
        int dchunk = sc ^ ((row >> xshift) & xmask);  // logical chunk landing in slot sc
        const u16* g = src + (size_t)row * strideE + dchunk * 8;
        async16(g, lds + (size_t)cbase * 8);
    }
}

// ------------------------------------------------- fused prep: cast x + 5 transposes
// grid 19456 blocks x 256 thr:
//   [0,8192)       x flat cast f32->bf16 (2M float4)
//   [8192,12288)   Wq  [2048][2048] -> WqlT rows 0..2047
//   [12288,13312)  Wl  [2048][512]  -> WqlT rows 2048..2559 (offset 4194304)
//   [13312,14336)  Wk  16x[512][128]-> WkvT rows 0..2047 (per-head [128][512])
//   [14336,15360)  Wv  16x[512][128]-> WkvT rows 2048..4095
//   [15360,19456)  Wo  [2048][2048] -> WoT
// Transpose is one-shot per 32x32 tile: float4 global reads (16B/lane),
// ushort4 transposed stores (8B/lane, 64B-contiguous per 8 lanes).
__global__ __launch_bounds__(256) void prep(const float* __restrict__ x,
                                            const float* __restrict__ Wq,
                                            const float* __restrict__ Wl,
                                            const float* __restrict__ Wk,
                                            const float* __restrict__ Wv,
                                            const float* __restrict__ Wo,
                                            u16* __restrict__ xb,
                                            u16* __restrict__ WqlT,
                                            u16* __restrict__ WkvT,
                                            u16* __restrict__ WoT) {
    const int t = blockIdx.x, tid = threadIdx.x;
    if (t < 8192) {
        int i = t * 256 + tid;
        float4 v = ((const float4*)x)[i];
        unsigned int lo = (unsigned int)f2b(v.x) | ((unsigned int)f2b(v.y) << 16);
        unsigned int hi = (unsigned int)f2b(v.z) | ((unsigned int)f2b(v.w) << 16);
        ((uint2*)xb)[i] = make_uint2(lo, hi);
        return;
    }
    __shared__ float tile[32][33];
    const float* src; u16* dst; int R, C, tY, tX;
    if (t < 12288)      { int tt = t - 8192;  src = Wq; dst = WqlT;           R = 2048; C = 2048; tY = tt >> 6; tX = tt & 63; }
    else if (t < 13312) { int tt = t - 12288; src = Wl; dst = WqlT + 4194304; R = 2048; C = 512;  tY = tt >> 4; tX = tt & 15; }
    else if (t < 14336) { int tt = t - 13312; int hh = tt >> 6; tt &= 63;
                          src = Wk + hh * 65536; dst = WkvT + hh * 65536;     R = 512;  C = 128;  tY = tt >> 2; tX = tt & 3; }
    else if (t < 15360) { int tt = t - 14336; int hh = tt >> 6; tt &= 63;
                          src = Wv + hh * 65536; dst = WkvT + 1048576 + hh * 65536;
                                                                              R = 512;  C = 128;  tY = tt >> 2; tX = tt & 3; }
    else                { int tt = t - 15360; src = Wo; dst = WoT;            R = 2048; C = 2048; tY = tt >> 6; tX = tt & 63; }
    const int r0 = tY * 32, c0 = tX * 32;
    // read 32x32 f32 tile in one shot: lane (rr=tid>>3, c4=tid&7) -> float4
    {
        const int rr = tid >> 3, c4 = tid & 7;
        float4 v4 = *(const float4*)&src[(size_t)(r0 + rr) * C + c0 + c4 * 4];
        tile[rr][c4 * 4 + 0] = v4.x;
        tile[rr][c4 * 4 + 1] = v4.y;
        tile[rr][c4 * 4 + 2] = v4.z;
        tile[rr][c4 * 4 + 3] = v4.w;
    }
    __syncthreads();
    // write transposed 32x32 bf16 in one shot: lane (rg=tid&7, cc=tid>>3)
    // stores 4 consecutive output elems (rows r0+rg*4..+3 of column c0+cc)
    {
        const int rg = tid & 7, cc = tid >> 3;
        ushort4 o4;
        o4.x = f2b(tile[rg * 4 + 0][cc]);
        o4.y = f2b(tile[rg * 4 + 1][cc]);
        o4.z = f2b(tile[rg * 4 + 2][cc]);
        o4.w = f2b(tile[rg * 4 + 3][cc]);
        *(ushort4*)&dst[(size_t)(c0 + cc) * R + r0 + rg * 4] = o4;
    }
}

// ---------------------------------------------------------------- GEMM
// C = A[M][K] @ Bt[N][K]^T + bias. Double-buffered LDS (prefetch-after-barrier:
// one barrier/iter; the vmcnt(0) drain of the prefetch overlaps the whole
// compute phase). LDS chunk-swizzled (slot = chunk ^ ((row>>1)&3)) so frag
// reads are 2-way max (free) instead of 8-way.
// Chunked bijective XCD swizzle (m204): each XCD gets a contiguous x-major
// chunk of the grid (= whole grid rows) -> its A-panels stay L2-resident,
// B-panels stream in lock-step across XCDs (L3 hits).
// STORE 2: f32 row-major to C1 (bias1)
// STORE 3: n<2048 -> bf16 (bias1 then *QSCALE) C1[m][n] (stride 2048);
//          n>=2048 -> bf16 C2[m][n-2048] (stride 512, bias2)
// STORE 4: n<2048 -> bf16 C1[m][n] (stride 2048, bias1); n>=2048 -> vt scatter
//          C2[((m>>11)*2048+(n-2048))*2048 + sigma(m&2047)] (bias2), 4-wide
//          vectorized; sigma swaps bits 2<->3 of the column within each
//          64-block so attn's PV A-frag k-slot order matches the in-register
//          permlane P-transpose (see attn_fused).
template<int STORE>
__global__ __launch_bounds__(256) void gemm_bt(const u16* __restrict__ A,
                                               const u16* __restrict__ Bt,
                                               const float* __restrict__ bias1,
                                               const float* __restrict__ bias2,
                                               void* __restrict__ C1,
                                               void* __restrict__ C2,
                                               int M, int N, int K) {
    __shared__ __align__(16) u16 As[2][128 * 32];
    __shared__ __align__(16) u16 Bs[2][128 * 32];
    const int tid = threadIdx.x, wave = tid >> 6, lane = tid & 63;
    const int quad = lane >> 4, m16 = lane & 15;
    // --- chunked bijective XCD swizzle (nwg % 8 == 0 for all our launches) ---
    const int gx = gridDim.x;
    const int nwg = gx * gridDim.y;
    int lin = blockIdx.x + gx * blockIdx.y;          // HW dispatch order; XCD = lin&7
    int xcd = lin & 7, pos = lin >> 3;
    int qq = nwg >> 3, rr2 = nwg & 7;
    int wg = (xcd < rr2) ? xcd * (qq + 1) + pos
                         : rr2 * (qq + 1) + (xcd - rr2) * qq + pos;
    const int m0 = (wg / gx) * 128, n0 = (wg % gx) * 128;
    const int wr = wave >> 1, wc = wave & 1;
    const int swz = (quad ^ ((m16 >> 1) & 3)) * 8;   // swizzled chunk offset for frag reads
    const u16* Ab = A + (size_t)m0 * K;
    const u16* Bb = Bt + (size_t)n0 * K;
    const int KI = K >> 5;

    stage_lds(Ab, K, As[0], wave, lane, 2, 3, 1, 2, 256);
    stage_lds(Bb, K, Bs[0], wave, lane, 2, 3, 1, 2, 256);

    f32x4 acc[4][4] = {};
    for (int it = 0; it < KI; ++it) {
        const int cur = it & 1;
        __syncthreads();   // tile `it` landed; prev compute done
        if (it + 1 < KI) {   // prefetch tile it+1 into the other buffer
            stage_lds(Ab + (it + 1) * 32, K, As[cur ^ 1], wave, lane, 2, 3, 1, 2, 256);
            stage_lds(Bb + (it + 1) * 32, K, Bs[cur ^ 1], wave, lane, 2, 3, 1, 2, 256);
        }
        short8 af[4], bfr[4];
        #pragma unroll
        for (int i = 0; i < 4; i++)
            af[i] = *(const short8*)&As[cur][(wr * 64 + i * 16 + m16) * 32 + swz];
        #pragma unroll
        for (int j = 0; j < 4; j++)
            bfr[j] = *(const short8*)&Bs[cur][(wc * 64 + j * 16 + m16) * 32 + swz];
        #pragma unroll
        for (int i = 0; i < 4; i++)
            #pragma unroll
            for (int j = 0; j < 4; j++)
                acc[i][j] = MFMA16(af[i], bfr[j], acc[i][j], 0, 0, 0);
    }
    const bool second = (n0 >= 2048);   // region is block-uniform (2048 % 128 == 0)
    #pragma unroll
    for (int j = 0; j < 4; j++) {
        int n = n0 + wc * 64 + j * 16 + m16;
        float bv;
        if constexpr (STORE == 2) bv = bias1[n];
        else bv = second ? bias2[n - 2048] : bias1[n];
        #pragma unroll
        for (int i = 0; i < 4; i++) {
            int mrow = m0 + wr * 64 + i * 16 + quad * 4;
            if constexpr (STORE == 4) {
                if (second) {
                    int n2 = n - 2048;
                    ushort4 pkv;
                    pkv.x = f2b(acc[i][j][0] + bv);
                    pkv.y = f2b(acc[i][j][1] + bv);
                    pkv.z = f2b(acc[i][j][2] + bv);
                    pkv.w = f2b(acc[i][j][3] + bv);
                    int c = mrow & 2047;
                    c = (c & ~12) | ((c & 4) << 1) | ((c & 8) >> 1);  // sigma: swap bits 2,3
                    *(ushort4*)&((u16*)C2)[((size_t)((m0 >> 11) * 2048 + n2)) * 2048 + c] = pkv;
                    continue;
                }
            }
            #pragma unroll
            for (int r = 0; r < 4; r++) {
                float v = acc[i][j][r] + bv;
                int m = mrow + r;
                if constexpr (STORE == 2)
                    ((float*)C1)[(size_t)m * N + n] = v;
                else if constexpr (STORE == 3) {
                    if (!second) ((u16*)C1)[(size_t)m * 2048 + n] = f2b(v * QSCALE);
                    else         ((u16*)C2)[(size_t)m * 512 + (n - 2048)] = f2b(v);
                } else {  // STORE == 4, first region
                    ((u16*)C1)[(size_t)m * 2048 + n] = f2b(v);
                }
            }
        }
    }
}

// ---------------------------------------------------------------- fused attention
// 4 waves/block, 32 q-rows/wave (128 q/block). 48KB LDS -> 3 blocks/CU
// (12 waves/CU vs round-6's 8): K double-buffered via global_load_lds;
// V single-buffered, reg-staged with ONE named float4 set (v0..v3 — no
// arrays, no lambda: round-3's scratch-spill bug came from by-ref float4
// arrays; every access here is a named register).
// Per iter: barrier (drains K(it)+V(it) loads issued a full compute phase
// ago) -> ds_write V(it) -> barrier (cheap: no outstanding vmem) -> issue
// K(it+1) gload_lds + V(it+1) reg loads -> compute. WAR on v0..v3 is safe:
// ds_write consumes the regs at issue, loads write back later.
// Grid is (bh, q): XCD = bh%8 -> per-XCD L2 holds 4 (b,h)-pairs' KV (4MB).
// Swapped QK^T: S^T = mfma(A=K, B=Q) so each lane holds a full P-row.
// P never touches LDS: 16 cvt_pk + 8 permlane32_swap per tile build the PV
// A-frags in registers; kv k-slot permutation (swap bits 2<->3 per 64-block)
// is baked into V by gemm_bt<4>'s sigma scatter.
// No-max softmax (|s'| << 115 in exp2 domain); Q pre-scaled by 1/sqrt(128)*log2e.
// Q,K: bf16 [4096][2048] (row = b*2048+t, col = h*128+d)
// Vt:  bf16 [4096][2048] (row = b*2048+h*128+d, col = sigma-permuted t)
// Ob:  bf16 [4096][2048]
__global__ __launch_bounds__(256, 3) void attn_fused(const u16* __restrict__ Q,
                                                     const u16* __restrict__ Kf,
                                                     const u16* __restrict__ Vt,
                                                     u16* __restrict__ Ob) {
    __shared__ __align__(16) u16 Kt[2][64 * 128];   // [dbuf][64 kv][128 d] (also Q stage)
    __shared__ __align__(16) u16 Vtile[128 * 64];   // [128 d][64 kv-slots] single buffer
    const int tid = threadIdx.x, wave = tid >> 6, lane = tid & 63;
    const int quad = lane >> 4, m16 = lane & 15;
    const int bh = blockIdx.x, b = bh >> 4, h = bh & 15;   // bh fast -> XCD = bh%8
    const int q0 = blockIdx.y * 128;
    const size_t grow = (size_t)b * SEQ;
    const u16* Kbase = Kf + grow * NHID + h * DHEAD;
    const u16* Vbase = Vt + (grow + h * DHEAD) * SEQ;

    // stage Q tile [128][128]: rows 0..63 -> Kt[0], rows 64..127 -> Kt[1]
    const u16* qsrc = Q + (grow + q0) * NHID + h * DHEAD;
    stage_lds(qsrc, NHID, Kt[0], wave, lane, 4, 15, 0, 4, 256);
    stage_lds(qsrc + (size_t)64 * NHID, NHID, Kt[1], wave, lane, 4, 15, 0, 4, 256);
    __syncthreads();
    short8 qf[2][4];
    {
        const u16* qbuf = Kt[wave >> 1];
        int rbase = (wave & 1) * 32;
        #pragma unroll
        for (int i = 0; i < 2; i++)
            #pragma unroll
            for (int c = 0; c < 4; c++)
                qf[i][c] = *(const short8*)&qbuf[(rbase + i * 16 + m16) * 128 +
                                                (((c * 4 + quad) ^ m16)) * 8];
    }
    __syncthreads();   // all waves done reading Q before kv tile 0 overwrites Kt[0]

    // V staging addresses: same mapping as stage_lds(...,3,7,0,4,256):
    // ci = rep*256 + wave*64 + lane; row = ci>>3; dchunk = (ci&7)^(row&7)
    const int ci0 = wave * 64 + lane;
    const int ci1 = ci0 + 256, ci2 = ci0 + 512, ci3 = ci0 + 768;
    const u16* vsrc0 = Vbase + (size_t)(ci0 >> 3) * SEQ + ((ci0 & 7) ^ ((ci0 >> 3) & 7)) * 8;
    const u16* vsrc1 = Vbase + (size_t)(ci1 >> 3) * SEQ + ((ci1 & 7) ^ ((ci1 >> 3) & 7)) * 8;
    const u16* vsrc2 = Vbase + (size_t)(ci2 >> 3) * SEQ + ((ci2 & 7) ^ ((ci2 >> 3) & 7)) * 8;
    const u16* vsrc3 = Vbase + (size_t)(ci3 >> 3) * SEQ + ((ci3 & 7) ^ ((ci3 >> 3) & 7)) * 8;
    u16* vdst0 = &Vtile[ci0 * 8];
    u16* vdst1 = &Vtile[ci1 * 8];
    u16* vdst2 = &Vtile[ci2 * 8];
    u16* vdst3 = &Vtile[ci3 * 8];

    // prologue: issue K(0) -> Kt[0] (gload_lds), V(0) -> named regs
    stage_lds(Kbase, NHID, Kt[0], wave, lane, 4, 15, 0, 4, 256);
    float4 v0 = *(const float4*)vsrc0;
    float4 v1 = *(const float4*)vsrc1;
    float4 v2 = *(const float4*)vsrc2;
    float4 v3 = *(const float4*)vsrc3;

    f32x4 o[2][8] = {};
    float lsum[2] = {};

    for (int it = 0; it < SEQ / 64; ++it) {
        const int cur = it & 1;
        __syncthreads();   // drains K(it) gload_lds + V(it) reg loads (issued one
                           // full compute phase ago); all waves done with PV(it-1)
        *(float4*)vdst0 = v0;          // V(it) regs -> LDS
        *(float4*)vdst1 = v1;
        *(float4*)vdst2 = v2;
        *(float4*)vdst3 = v3;
        __syncthreads();   // Vtile visible (cheap: no outstanding vmem here)
        if (it + 1 < SEQ / 64) {       // prefetch issued AFTER the barrier pair
            stage_lds(Kbase + (size_t)(it + 1) * 64 * NHID, NHID, Kt[cur ^ 1],
                      wave, lane, 4, 15, 0, 4, 256);
            const int off = (it + 1) * 64;
            v0 = *(const float4*)(vsrc0 + off);
            v1 = *(const float4*)(vsrc1 + off);
            v2 = *(const float4*)(vsrc2 + off);
            v3 = *(const float4*)(vsrc3 + off);
        }
        const u16* kt = Kt[cur];
        const u16* vt = Vtile;

        // S^T = K Q^T : s[i][j] holds q col = i*16+m16, kv row = j*16+quad*4+r
        f32x4 s[2][4] = {};
        __builtin_amdgcn_s_setprio(1);
        #pragma unroll
        for (int c = 0; c < 4; c++)
            #pragma unroll
            for (int j = 0; j < 4; j++) {
                short8 kb = *(const short8*)&kt[(j * 16 + m16) * 128 +
                                               (((c * 4 + quad) ^ m16)) * 8];
                s[0][j] = MFMA16(kb, qf[0][c], s[0][j], 0, 0, 0);
                s[1][j] = MFMA16(kb, qf[1][c], s[1][j], 0, 0, 0);
            }
        __builtin_amdgcn_s_setprio(0);

        // p = exp2(s) (scale pre-folded into Q); full P-row is lane-local.
        // Pack to bf16 pairs: pk[i][j][w] = (p[4j+2w], p[4j+2w+1]).
        uint32_t pk[2][4][2];
        #pragma unroll
        for (int i = 0; i < 2; i++) {
            float rs = 0.f;
            #pragma unroll
            for (int j = 0; j < 4; j++) {
                float p0 = EXP2(s[i][j][0]);
                float p1 = EXP2(s[i][j][1]);
                float p2 = EXP2(s[i][j][2]);
                float p3 = EXP2(s[i][j][3]);
                rs += (p0 + p1) + (p2 + p3);
                pk[i][j][0] = cvt_pk_bf16(p0, p1);
                pk[i][j][1] = cvt_pk_bf16(p2, p3);
            }
            lsum[i] += rs;
        }

        // O += P @ V. A-frag built in-register: one permlane32_swap per reg pair
        // gives pa = [A'w0, A'w1, B'w0, B'w1] uniformly for all lanes (k-slot
        // order matches the sigma-permuted V layout).
        __builtin_amdgcn_s_setprio(1);
        #pragma unroll
        for (int c2 = 0; c2 < 2; c2++) {
            short8 pa[2];
            #pragma unroll
            for (int i = 0; i < 2; i++) {
                union { uint32_t u[4]; short8 s8; } pu;
#if __has_builtin(__builtin_amdgcn_permlane32_swap)
                auto r0 = __builtin_amdgcn_permlane32_swap(pk[i][2 * c2][0],
                                                           pk[i][2 * c2 + 1][0],
                                                           false, false);
                auto r1 = __builtin_amdgcn_permlane32_swap(pk[i][2 * c2][1],
                                                           pk[i][2 * c2 + 1][1],
                                                           false, false);
                pu.u[0] = r0[0]; pu.u[1] = r1[0]; pu.u[2] = r0[1]; pu.u[3] = r1[1];
#else
                uint32_t jl0 = pk[i][2 * c2][0],     jl1 = pk[i][2 * c2][1];
                uint32_t jh0 = pk[i][2 * c2 + 1][0], jh1 = pk[i][2 * c2 + 1][1];
                uint32_t sl0 = __shfl_xor(jl0, 32), sl1 = __shfl_xor(jl1, 32);
                uint32_t sh0 = __shfl_xor(jh0, 32), sh1 = __shfl_xor(jh1, 32);
                const bool low = lane < 32;
                pu.u[0] = low ? jl0 : sh0;
                pu.u[1] = low ? jl1 : sh1;
                pu.u[2] = low ? sl0 : jh0;
                pu.u[3] = low ? sl1 : jh1;
#endif
                pa[i] = pu.s8;
            }
            #pragma unroll
            for (int jd = 0; jd < 8; jd++) {
                short8 vb = *(const short8*)&vt[(jd * 16 + m16) * 64 +
                                               (((c2 * 4 + quad) ^ (m16 & 7))) * 8];
                o[0][jd] = MFMA16(pa[0], vb, o[0][jd], 0, 0, 0);
                o[1][jd] = MFMA16(pa[1], vb, o[1][jd], 0, 0, 0);
            }
        }
        __builtin_amdgcn_s_setprio(0);
    }

    // lane holds partial row-sum for q = i*16+m16; reduce across quads (lanes
    // +-16, +-32), then redistribute to the o-layout rows (quad*4+r) via shfl.
    #pragma unroll
    for (int i = 0; i < 2; i++) {
        float v = lsum[i];
        v += __shfl_xor(v, 16);
        v += __shfl_xor(v, 32);
        lsum[i] = v;
    }
    #pragma unroll
    for (int i = 0; i < 2; i++) {
        float inv[4];
        #pragma unroll
        for (int r = 0; r < 4; r++)
            inv[r] = 1.f / __shfl(lsum[i], quad * 4 + r);
        #pragma unroll
        for (int jd = 0; jd < 8; jd++)
            #pragma unroll
            for (int r = 0; r < 4; r++) {
                int t = q0 + wave * 32 + i * 16 + quad * 4 + r;
                int d = jd * 16 + m16;
                Ob[(grow + t) * NHID + h * DHEAD + d] = f2b(o[i][jd][r] * inv[r]);
            }
    }
}

// ---------------------------------------------------------------- launch
extern "C" void kernel_launch(void* const* d_in, const int* in_sizes, int n_in,
                              void* d_out, int out_size, void* d_ws, size_t ws_size,
                              hipStream_t stream) {
    const float* x  = (const float*)d_in[0];
    const float* Wq = (const float*)d_in[1];
    const float* bq = (const float*)d_in[2];
    const float* Wl = (const float*)d_in[3];
    const float* bl = (const float*)d_in[4];
    const float* Wk = (const float*)d_in[5];
    const float* bk = (const float*)d_in[6];
    const float* Wv = (const float*)d_in[7];
    const float* bv = (const float*)d_in[8];
    const float* Wo = (const float*)d_in[9];
    const float* bo = (const float*)d_in[10];
    float* out = (float*)d_out;

    u16* w = (u16*)d_ws;
    u16* xb    = w;                   // 8388608 elems (16 MB)
    u16* WqlT  = xb    + 8388608;     // [2560][2048] = 5242880 (10.5 MB)
    u16* WkvT  = WqlT  + 5242880;     // [4096][512]  = 2097152 (4 MB)
    u16* WoT   = WkvT  + 2097152;     // [2048][2048] = 4194304 (8 MB)
    u16* qb    = WoT   + 4194304;     // 8388608 (16 MB)
    u16* kb    = qb    + 8388608;     // 8388608 (16 MB)
    u16* vt    = kb    + 8388608;     // 8388608 (16 MB, transposed+sigma-permuted V)
    u16* lat   = vt    + 8388608;     // [4096][512] = 2097152 (4 MB)
    u16* attnb = xb;                  // alias: xb dead after QL GEMM
    // total 90 MB

    prep<<<19456, 256, 0, stream>>>(x, Wq, Wl, Wk, Wv, Wo, xb, WqlT, WkvT, WoT);

    // fused Q + latent projection: [4096][2048] x [2560][2048]^T
    gemm_bt<3><<<dim3(20, 32), 256, 0, stream>>>(xb, WqlT, bq, bl, qb, lat,
                                                 NROWS, 2560, 2048);
    // fused K + V back-projection: [4096][512] x [4096][512]^T
    gemm_bt<4><<<dim3(32, 32), 256, 0, stream>>>(lat, WkvT, bk, bv, kb, vt,
                                                 NROWS, 4096, 512);

    // grid (bh, q): XCD = bh%8 -> per-XCD L2 holds 4 (b,h)-pairs' KV (4MB)
    attn_fused<<<dim3(32, 16), 256, 0, stream>>>(qb, kb, vt, attnb);

    gemm_bt<2><<<dim3(16, 32), 256, 0, stream>>>(attnb, WoT, bo, nullptr, out, nullptr,
                                                 NROWS, 2048, 2048);
}

// Round 8
// 335.374 us; speedup vs baseline: 1.1545x; 1.1545x over previous
//
#include <hip/hip_runtime.h>
#include <hip/hip_bf16.h>
#include <cstdint>

#define SEQ     2048
#define NHID    2048
#define NLAT    512
#define NHEAD   16
#define DHEAD   128
#define NBATCH  2
#define NROWS   (NBATCH*SEQ)   // 4096

typedef unsigned short u16;
typedef __attribute__((ext_vector_type(8))) short short8;
typedef __attribute__((ext_vector_type(4))) float f32x4;

#define MFMA16 __builtin_amdgcn_mfma_f32_16x16x32_bf16

// 1/sqrt(128) * log2(e): folded into the Q projection so attn softmax is a raw exp2
#define QSCALE 0.12751743f

#if __has_builtin(__builtin_amdgcn_exp2f)
#define EXP2(x) __builtin_amdgcn_exp2f(x)
#else
#define EXP2(x) __expf((x) * 0.6931471805599453f)
#endif

__device__ __forceinline__ u16 f2b(float f) {
    uint32_t u = __float_as_uint(f);
    uint32_t r = (u + 0x7fffu + ((u >> 16) & 1u)) >> 16;   // RNE
    return (u16)r;
}

// HW packed f32->bf16 (RNE): lo = bf16(a), hi = bf16(b)
__device__ __forceinline__ uint32_t cvt_pk_bf16(float a, float b) {
    uint32_t r;
    asm("v_cvt_pk_bf16_f32 %0, %1, %2" : "=v"(r) : "v"(a), "v"(b));
    return r;
}

__device__ __forceinline__ void async16(const u16* g, u16* l) {
    __builtin_amdgcn_global_load_lds(
        (const __attribute__((address_space(1))) unsigned int*)g,
        (__attribute__((address_space(3))) unsigned int*)l, 16, 0, 0);
}

// Stage a tile of [rows][cols] bf16 (cols = chunks-of-8 * 8) from global (row
// stride strideE elems) into LDS, 16B per lane, wave-uniform LDS base.
// Logical chunk LC of row r is stored at slot LC ^ ((r >> xshift) & xmask).
__device__ __forceinline__ void stage_lds(const u16* __restrict__ src, size_t strideE,
                                          u16* lds, int wave, int lane,
                                          int log2cpr, int xmask, int xshift,
                                          int reps, int nlanes) {
    const int cmask = (1 << log2cpr) - 1;
    for (int rep = 0; rep < reps; ++rep) {
        int cbase = rep * nlanes + wave * 64;     // wave-uniform
        int ci = cbase + lane;
        int row = ci >> log2cpr;
        int sc = ci & cmask;
        int dchunk = sc ^ ((row >> xshift) & xmask);  // logical chunk landing in slot sc
        const u16* g = src + (size_t)row * strideE + dchunk * 8;
        async16(g, lds + (size_t)cbase * 8);
    }
}

// ------------------------------------------------- fused prep: cast x + 5 transposes
// grid 19456 blocks x 256 thr:
//   [0,8192)       x flat cast f32->bf16 (2M float4)
//   [8192,12288)   Wq  [2048][2048] -> WqlT rows 0..2047
//   [12288,13312)  Wl  [2048][512]  -> WqlT rows 2048..2559 (offset 4194304)
//   [13312,14336)  Wk  16x[512][128]-> WkvT rows 0..2047 (per-head [128][512])
//   [14336,15360)  Wv  16x[512][128]-> WkvT rows 2048..4095
//   [15360,19456)  Wo  [2048][2048] -> WoT
// Transpose is one-shot per 32x32 tile: float4 global reads (16B/lane),
// ushort4 transposed stores (8B/lane, 64B-contiguous per 8 lanes).
__global__ __launch_bounds__(256) void prep(const float* __restrict__ x,
                                            const float* __restrict__ Wq,
                                            const float* __restrict__ Wl,
                                            const float* __restrict__ Wk,
                                            const float* __restrict__ Wv,
                                            const float* __restrict__ Wo,
                                            u16* __restrict__ xb,
                                            u16* __restrict__ WqlT,
                                            u16* __restrict__ WkvT,
                                            u16* __restrict__ WoT) {
    const int t = blockIdx.x, tid = threadIdx.x;
    if (t < 8192) {
        int i = t * 256 + tid;
        float4 v = ((const float4*)x)[i];
        unsigned int lo = (unsigned int)f2b(v.x) | ((unsigned int)f2b(v.y) << 16);
        unsigned int hi = (unsigned int)f2b(v.z) | ((unsigned int)f2b(v.w) << 16);
        ((uint2*)xb)[i] = make_uint2(lo, hi);
        return;
    }
    __shared__ float tile[32][33];
    const float* src; u16* dst; int R, C, tY, tX;
    if (t < 12288)      { int tt = t - 8192;  src = Wq; dst = WqlT;           R = 2048; C = 2048; tY = tt >> 6; tX = tt & 63; }
    else if (t < 13312) { int tt = t - 12288; src = Wl; dst = WqlT + 4194304; R = 2048; C = 512;  tY = tt >> 4; tX = tt & 15; }
    else if (t < 14336) { int tt = t - 13312; int hh = tt >> 6; tt &= 63;
                          src = Wk + hh * 65536; dst = WkvT + hh * 65536;     R = 512;  C = 128;  tY = tt >> 2; tX = tt & 3; }
    else if (t < 15360) { int tt = t - 14336; int hh = tt >> 6; tt &= 63;
                          src = Wv + hh * 65536; dst = WkvT + 1048576 + hh * 65536;
                                                                              R = 512;  C = 128;  tY = tt >> 2; tX = tt & 3; }
    else                { int tt = t - 15360; src = Wo; dst = WoT;            R = 2048; C = 2048; tY = tt >> 6; tX = tt & 63; }
    const int r0 = tY * 32, c0 = tX * 32;
    // read 32x32 f32 tile in one shot: lane (rr=tid>>3, c4=tid&7) -> float4
    {
        const int rr = tid >> 3, c4 = tid & 7;
        float4 v4 = *(const float4*)&src[(size_t)(r0 + rr) * C + c0 + c4 * 4];
        tile[rr][c4 * 4 + 0] = v4.x;
        tile[rr][c4 * 4 + 1] = v4.y;
        tile[rr][c4 * 4 + 2] = v4.z;
        tile[rr][c4 * 4 + 3] = v4.w;
    }
    __syncthreads();
    // write transposed 32x32 bf16 in one shot: lane (rg=tid&7, cc=tid>>3)
    // stores 4 consecutive output elems (rows r0+rg*4..+3 of column c0+cc)
    {
        const int rg = tid & 7, cc = tid >> 3;
        ushort4 o4;
        o4.x = f2b(tile[rg * 4 + 0][cc]);
        o4.y = f2b(tile[rg * 4 + 1][cc]);
        o4.z = f2b(tile[rg * 4 + 2][cc]);
        o4.w = f2b(tile[rg * 4 + 3][cc]);
        *(ushort4*)&dst[(size_t)(c0 + cc) * R + r0 + rg * 4] = o4;
    }
}

// ---------------------------------------------------------------- GEMM
// C = A[M][K] @ Bt[N][K]^T + bias. Double-buffered LDS (prefetch-after-barrier:
// one barrier/iter; the vmcnt(0) drain of the prefetch overlaps the whole
// compute phase). Template BK = K-step (32 or 64): BK=64 halves the number of
// barrier-drains for K=2048 GEMMs (grids there give only 2-2.5 blocks/CU, so
// the 64KB LDS cost is free — occupancy is grid-limited, not LDS-limited).
// LDS chunk-swizzled so frag reads are 2-way max (free):
//   BK=32: slot = chunk ^ ((row>>1)&3);  BK=64: slot = chunk ^ (row&7)
//   (BK=64 pattern is byte-identical in structure to attn's Vtile reads,
//    which measure 0 bank conflicts).
// Chunked bijective XCD swizzle (m204): each XCD gets a contiguous x-major
// chunk of the grid -> A-panels stay L2-resident.
// STORE 2: f32 row-major to C1 (bias1)
// STORE 3: n<2048 -> bf16 (bias1 then *QSCALE) C1[m][n] (stride 2048);
//          n>=2048 -> bf16 C2[m][n-2048] (stride 512, bias2)
// STORE 4: n<2048 -> bf16 C1[m][n] (stride 2048, bias1); n>=2048 -> vt scatter
//          C2[((m>>11)*2048+(n-2048))*2048 + sigma(m&2047)] (bias2), 4-wide
//          vectorized; sigma swaps bits 2<->3 of the column within each
//          64-block (matches attn's in-register permlane P-transpose).
template<int STORE, int BK>
__global__ __launch_bounds__(256) void gemm_bt(const u16* __restrict__ A,
                                               const u16* __restrict__ Bt,
                                               const float* __restrict__ bias1,
                                               const float* __restrict__ bias2,
                                               void* __restrict__ C1,
                                               void* __restrict__ C2,
                                               int M, int N, int K) {
    __shared__ __align__(16) u16 As[2][128 * BK];
    __shared__ __align__(16) u16 Bs[2][128 * BK];
    const int tid = threadIdx.x, wave = tid >> 6, lane = tid & 63;
    const int quad = lane >> 4, m16 = lane & 15;
    // --- chunked bijective XCD swizzle (nwg % 8 == 0 for all our launches) ---
    const int gx = gridDim.x;
    const int nwg = gx * gridDim.y;
    int lin = blockIdx.x + gx * blockIdx.y;          // HW dispatch order; XCD = lin&7
    int xcd = lin & 7, pos = lin >> 3;
    int qq = nwg >> 3, rr2 = nwg & 7;
    int wg = (xcd < rr2) ? xcd * (qq + 1) + pos
                         : rr2 * (qq + 1) + (xcd - rr2) * qq + pos;
    const int m0 = (wg / gx) * 128, n0 = (wg % gx) * 128;
    const int wr = wave >> 1, wc = wave & 1;
    const u16* Ab = A + (size_t)m0 * K;
    const u16* Bb = Bt + (size_t)n0 * K;
    const int KI = K / BK;

    // stage one 128xBK tile (both variants: 16B/lane, chunk-swizzled)
    auto stage = [&](const u16* src, u16* buf) {
        if constexpr (BK == 32) stage_lds(src, K, buf, wave, lane, 2, 3, 1, 2, 256);
        else                    stage_lds(src, K, buf, wave, lane, 3, 7, 0, 4, 256);
    };

    stage(Ab, As[0]);
    stage(Bb, Bs[0]);

    f32x4 acc[4][4] = {};
    for (int it = 0; it < KI; ++it) {
        const int cur = it & 1;
        __syncthreads();   // tile `it` landed; prev compute done
        if (it + 1 < KI) {   // prefetch tile it+1 into the other buffer
            stage(Ab + (it + 1) * BK, As[cur ^ 1]);
            stage(Bb + (it + 1) * BK, Bs[cur ^ 1]);
        }
        if constexpr (BK == 32) {
            const int swz = (quad ^ ((m16 >> 1) & 3)) * 8;
            short8 af[4], bfr[4];
            #pragma unroll
            for (int i = 0; i < 4; i++)
                af[i] = *(const short8*)&As[cur][(wr * 64 + i * 16 + m16) * 32 + swz];
            #pragma unroll
            for (int j = 0; j < 4; j++)
                bfr[j] = *(const short8*)&Bs[cur][(wc * 64 + j * 16 + m16) * 32 + swz];
            #pragma unroll
            for (int i = 0; i < 4; i++)
                #pragma unroll
                for (int j = 0; j < 4; j++)
                    acc[i][j] = MFMA16(af[i], bfr[j], acc[i][j], 0, 0, 0);
        } else {
            #pragma unroll
            for (int kk = 0; kk < 2; kk++) {
                const int swz = ((kk * 4 + quad) ^ (m16 & 7)) * 8;
                short8 af[4], bfr[4];
                #pragma unroll
                for (int i = 0; i < 4; i++)
                    af[i] = *(const short8*)&As[cur][(wr * 64 + i * 16 + m16) * 64 + swz];
                #pragma unroll
                for (int j = 0; j < 4; j++)
                    bfr[j] = *(const short8*)&Bs[cur][(wc * 64 + j * 16 + m16) * 64 + swz];
                #pragma unroll
                for (int i = 0; i < 4; i++)
                    #pragma unroll
                    for (int j = 0; j < 4; j++)
                        acc[i][j] = MFMA16(af[i], bfr[j], acc[i][j], 0, 0, 0);
            }
        }
    }
    const bool second = (n0 >= 2048);   // region is block-uniform (2048 % 128 == 0)
    #pragma unroll
    for (int j = 0; j < 4; j++) {
        int n = n0 + wc * 64 + j * 16 + m16;
        float bv;
        if constexpr (STORE == 2) bv = bias1[n];
        else bv = second ? bias2[n - 2048] : bias1[n];
        #pragma unroll
        for (int i = 0; i < 4; i++) {
            int mrow = m0 + wr * 64 + i * 16 + quad * 4;
            if constexpr (STORE == 4) {
                if (second) {
                    int n2 = n - 2048;
                    ushort4 pkv;
                    pkv.x = f2b(acc[i][j][0] + bv);
                    pkv.y = f2b(acc[i][j][1] + bv);
                    pkv.z = f2b(acc[i][j][2] + bv);
                    pkv.w = f2b(acc[i][j][3] + bv);
                    int c = mrow & 2047;
                    c = (c & ~12) | ((c & 4) << 1) | ((c & 8) >> 1);  // sigma: swap bits 2,3
                    *(ushort4*)&((u16*)C2)[((size_t)((m0 >> 11) * 2048 + n2)) * 2048 + c] = pkv;
                    continue;
                }
            }
            #pragma unroll
            for (int r = 0; r < 4; r++) {
                float v = acc[i][j][r] + bv;
                int m = mrow + r;
                if constexpr (STORE == 2)
                    ((float*)C1)[(size_t)m * N + n] = v;
                else if constexpr (STORE == 3) {
                    if (!second) ((u16*)C1)[(size_t)m * 2048 + n] = f2b(v * QSCALE);
                    else         ((u16*)C2)[(size_t)m * 512 + (n - 2048)] = f2b(v);
                } else {  // STORE == 4, first region
                    ((u16*)C1)[(size_t)m * 2048 + n] = f2b(v);
                }
            }
        }
    }
}

// ---------------------------------------------------------------- fused attention
// (round-6 version — known 75.8us. Grid is 512 blocks = exactly 2 blocks/CU:
// occupancy is grid-limited, so LDS-freeing restructures cannot help.)
// 4 waves/block, 32 q-rows/wave (128 q/block). K/V tiles double-buffered (64KB
// LDS, 2 blocks/CU): per iter, barrier FIRST (drains tile it), then issue
// async prefetch of tile it+1 into the other buffer, then compute on tile it.
// Grid is (bh, q): XCD = bh%8, so each XCD's L2 holds 4 (b,h)-pairs' KV (4MB)
// -> KV re-reads across the 16 q-blocks are L2 hits instead of HBM.
// Swapped QK^T: S^T = mfma(A=K, B=Q) so each lane holds a full P-row
// (q = i*16+m16, 16 kv values per j). P never touches LDS: 16 cvt_pk +
// 8 permlane32_swap per tile build the PV A-frags in registers. The implied
// kv k-slot permutation (swap bits 2<->3 within each 64-block) is baked into
// the V layout by gemm_bt<4>'s scatter, so V staging/reads are unchanged.
// No-max softmax (|s'| << 115 in exp2 domain); Q pre-scaled by 1/sqrt(128)*log2e.
// Row-sum: one scalar/lane/half, reduced across quads after the kv loop.
// Q,K: bf16 [4096][2048] (row = b*2048+t, col = h*128+d)
// Vt:  bf16 [4096][2048] (row = b*2048+h*128+d, col = sigma-permuted t)
// Ob:  bf16 [4096][2048]
__global__ __launch_bounds__(256, 2) void attn_fused(const u16* __restrict__ Q,
                                                     const u16* __restrict__ Kf,
                                                     const u16* __restrict__ Vt,
                                                     u16* __restrict__ Ob) {
    __shared__ __align__(16) u16 Kt[2][64 * 128];     // [dbuf][64 kv][128 d] (also Q stage)
    __shared__ __align__(16) u16 Vtile[2][128 * 64];  // [dbuf][128 d][64 kv-slots]
    const int tid = threadIdx.x, wave = tid >> 6, lane = tid & 63;
    const int quad = lane >> 4, m16 = lane & 15;
    const int bh = blockIdx.x, b = bh >> 4, h = bh & 15;   // bh fast -> XCD = bh%8
    const int q0 = blockIdx.y * 128;
    const size_t grow = (size_t)b * SEQ;
    const u16* Kbase = Kf + grow * NHID + h * DHEAD;
    const u16* Vbase = Vt + (grow + h * DHEAD) * SEQ;

    // stage Q tile [128][128]: rows 0..63 -> Kt[0], rows 64..127 -> Kt[1]
    const u16* qsrc = Q + (grow + q0) * NHID + h * DHEAD;
    stage_lds(qsrc, NHID, Kt[0], wave, lane, 4, 15, 0, 4, 256);
    stage_lds(qsrc + (size_t)64 * NHID, NHID, Kt[1], wave, lane, 4, 15, 0, 4, 256);
    __syncthreads();
    short8 qf[2][4];
    {
        const u16* qbuf = Kt[wave >> 1];
        int rbase = (wave & 1) * 32;
        #pragma unroll
        for (int i = 0; i < 2; i++)
            #pragma unroll
            for (int c = 0; c < 4; c++)
                qf[i][c] = *(const short8*)&qbuf[(rbase + i * 16 + m16) * 128 +
                                                (((c * 4 + quad) ^ m16)) * 8];
    }
    __syncthreads();   // all waves done reading Q before kv tile 0 overwrites Kt[0]

    // issue kv tile 0 into buffer 0
    stage_lds(Kbase, NHID, Kt[0], wave, lane, 4, 15, 0, 4, 256);
    stage_lds(Vbase, SEQ, Vtile[0], wave, lane, 3, 7, 0, 4, 256);

    f32x4 o[2][8] = {};
    float lsum[2] = {};

    for (int it = 0; it < SEQ / 64; ++it) {
        const int cur = it & 1;
        __syncthreads();   // tile `it` landed (vmcnt drain overlapped w/ prev compute)
        if (it + 1 < SEQ / 64) {   // async prefetch of tile it+1 into other buffer
            stage_lds(Kbase + (size_t)(it + 1) * 64 * NHID, NHID, Kt[cur ^ 1],
                      wave, lane, 4, 15, 0, 4, 256);
            stage_lds(Vbase + (it + 1) * 64, SEQ, Vtile[cur ^ 1],
                      wave, lane, 3, 7, 0, 4, 256);
        }
        const u16* kt = Kt[cur];
        const u16* vt = Vtile[cur];

        // S^T = K Q^T : s[i][j] holds q col = i*16+m16, kv row = j*16+quad*4+r
        f32x4 s[2][4] = {};
        __builtin_amdgcn_s_setprio(1);
        #pragma unroll
        for (int c = 0; c < 4; c++)
            #pragma unroll
            for (int j = 0; j < 4; j++) {
                short8 kb = *(const short8*)&kt[(j * 16 + m16) * 128 +
                                               (((c * 4 + quad) ^ m16)) * 8];
                s[0][j] = MFMA16(kb, qf[0][c], s[0][j], 0, 0, 0);
                s[1][j] = MFMA16(kb, qf[1][c], s[1][j], 0, 0, 0);
            }
        __builtin_amdgcn_s_setprio(0);

        // p = exp2(s) (scale pre-folded into Q); full P-row is lane-local.
        // Pack to bf16 pairs: pk[i][j][w] = (p[4j+2w], p[4j+2w+1]).
        uint32_t pk[2][4][2];
        #pragma unroll
        for (int i = 0; i < 2; i++) {
            float rs = 0.f;
            #pragma unroll
            for (int j = 0; j < 4; j++) {
                float p0 = EXP2(s[i][j][0]);
                float p1 = EXP2(s[i][j][1]);
                float p2 = EXP2(s[i][j][2]);
                float p3 = EXP2(s[i][j][3]);
                rs += (p0 + p1) + (p2 + p3);
                pk[i][j][0] = cvt_pk_bf16(p0, p1);
                pk[i][j][1] = cvt_pk_bf16(p2, p3);
            }
            lsum[i] += rs;
        }

        // O += P @ V. A-frag built in-register: one permlane32_swap per reg pair
        // gives pa = [A'w0, A'w1, B'w0, B'w1] uniformly for all lanes (k-slot
        // order matches the sigma-permuted V layout).
        __builtin_amdgcn_s_setprio(1);
        #pragma unroll
        for (int c2 = 0; c2 < 2; c2++) {
            short8 pa[2];
            #pragma unroll
            for (int i = 0; i < 2; i++) {
                union { uint32_t u[4]; short8 s8; } pu;
#if __has_builtin(__builtin_amdgcn_permlane32_swap)
                auto r0 = __builtin_amdgcn_permlane32_swap(pk[i][2 * c2][0],
                                                           pk[i][2 * c2 + 1][0],
                                                           false, false);
                auto r1 = __builtin_amdgcn_permlane32_swap(pk[i][2 * c2][1],
                                                           pk[i][2 * c2 + 1][1],
                                                           false, false);
                pu.u[0] = r0[0]; pu.u[1] = r1[0]; pu.u[2] = r0[1]; pu.u[3] = r1[1];
#else
                uint32_t jl0 = pk[i][2 * c2][0],     jl1 = pk[i][2 * c2][1];
                uint32_t jh0 = pk[i][2 * c2 + 1][0], jh1 = pk[i][2 * c2 + 1][1];
                uint32_t sl0 = __shfl_xor(jl0, 32), sl1 = __shfl_xor(jl1, 32);
                uint32_t sh0 = __shfl_xor(jh0, 32), sh1 = __shfl_xor(jh1, 32);
                const bool low = lane < 32;
                pu.u[0] = low ? jl0 : sh0;
                pu.u[1] = low ? jl1 : sh1;
                pu.u[2] = low ? sl0 : jh0;
                pu.u[3] = low ? sl1 : jh1;
#endif
                pa[i] = pu.s8;
            }
            #pragma unroll
            for (int jd = 0; jd < 8; jd++) {
                short8 vb = *(const short8*)&vt[(jd * 16 + m16) * 64 +
                                               (((c2 * 4 + quad) ^ (m16 & 7))) * 8];
                o[0][jd] = MFMA16(pa[0], vb, o[0][jd], 0, 0, 0);
                o[1][jd] = MFMA16(pa[1], vb, o[1][jd], 0, 0, 0);
            }
        }
        __builtin_amdgcn_s_setprio(0);
    }

    // lane holds partial row-sum for q = i*16+m16; reduce across quads (lanes
    // +-16, +-32), then redistribute to the o-layout rows (quad*4+r) via shfl.
    #pragma unroll
    for (int i = 0; i < 2; i++) {
        float v = lsum[i];
        v += __shfl_xor(v, 16);
        v += __shfl_xor(v, 32);
        lsum[i] = v;
    }
    #pragma unroll
    for (int i = 0; i < 2; i++) {
        float inv[4];
        #pragma unroll
        for (int r = 0; r < 4; r++)
            inv[r] = 1.f / __shfl(lsum[i], quad * 4 + r);
        #pragma unroll
        for (int jd = 0; jd < 8; jd++)
            #pragma unroll
            for (int r = 0; r < 4; r++) {
                int t = q0 + wave * 32 + i * 16 + quad * 4 + r;
                int d = jd * 16 + m16;
                Ob[(grow + t) * NHID + h * DHEAD + d] = f2b(o[i][jd][r] * inv[r]);
            }
    }
}

// ---------------------------------------------------------------- launch
extern "C" void kernel_launch(void* const* d_in, const int* in_sizes, int n_in,
                              void* d_out, int out_size, void* d_ws, size_t ws_size,
                              hipStream_t stream) {
    const float* x  = (const float*)d_in[0];
    const float* Wq = (const float*)d_in[1];
    const float* bq = (const float*)d_in[2];
    const float* Wl = (const float*)d_in[3];
    const float* bl = (const float*)d_in[4];
    const float* Wk = (const float*)d_in[5];
    const float* bk = (const float*)d_in[6];
    const float* Wv = (const float*)d_in[7];
    const float* bv = (const float*)d_in[8];
    const float* Wo = (const float*)d_in[9];
    const float* bo = (const float*)d_in[10];
    float* out = (float*)d_out;

    u16* w = (u16*)d_ws;
    u16* xb    = w;                   // 8388608 elems (16 MB)
    u16* WqlT  = xb    + 8388608;     // [2560][2048] = 5242880 (10.5 MB)
    u16* WkvT  = WqlT  + 5242880;     // [4096][512]  = 2097152 (4 MB)
    u16* WoT   = WkvT  + 2097152;     // [2048][2048] = 4194304 (8 MB)
    u16* qb    = WoT   + 4194304;     // 8388608 (16 MB)
    u16* kb    = qb    + 8388608;     // 8388608 (16 MB)
    u16* vt    = kb    + 8388608;     // 8388608 (16 MB, transposed+sigma-permuted V)
    u16* lat   = vt    + 8388608;     // [4096][512] = 2097152 (4 MB)
    u16* attnb = xb;                  // alias: xb dead after QL GEMM
    // total 90 MB

    prep<<<19456, 256, 0, stream>>>(x, Wq, Wl, Wk, Wv, Wo, xb, WqlT, WkvT, WoT);

    // fused Q + latent projection: [4096][2048] x [2560][2048]^T  (BK=64)
    gemm_bt<3, 64><<<dim3(20, 32), 256, 0, stream>>>(xb, WqlT, bq, bl, qb, lat,
                                                     NROWS, 2560, 2048);
    // fused K + V back-projection: [4096][512] x [4096][512]^T  (BK=32: K short,
    // grid 1024 = 4 blocks/CU — BK=64's 64KB LDS would cap it at 2)
    gemm_bt<4, 32><<<dim3(32, 32), 256, 0, stream>>>(lat, WkvT, bk, bv, kb, vt,
                                                     NROWS, 4096, 512);

    // grid (bh, q): XCD = bh%8 -> per-XCD L2 holds 4 (b,h)-pairs' KV (4MB)
    attn_fused<<<dim3(32, 16), 256, 0, stream>>>(qb, kb, vt, attnb);

    // output projection  (BK=64)
    gemm_bt<2, 64><<<dim3(16, 32), 256, 0, stream>>>(attnb, WoT, bo, nullptr, out, nullptr,
                                                     NROWS, 2048, 2048);
}

// Round 9
// 328.289 us; speedup vs baseline: 1.1794x; 1.0216x over previous
//
#include <hip/hip_runtime.h>
#include <hip/hip_bf16.h>
#include <cstdint>

#define SEQ     2048
#define NHID    2048
#define NLAT    512
#define NHEAD   16
#define DHEAD   128
#define NBATCH  2
#define NROWS   (NBATCH*SEQ)   // 4096

typedef unsigned short u16;
typedef __attribute__((ext_vector_type(8))) short short8;
typedef __attribute__((ext_vector_type(4))) float f32x4;

#define MFMA16 __builtin_amdgcn_mfma_f32_16x16x32_bf16

// 1/sqrt(128) * log2(e): folded into the Q projection so attn softmax is a raw exp2
#define QSCALE 0.12751743f

#if __has_builtin(__builtin_amdgcn_exp2f)
#define EXP2(x) __builtin_amdgcn_exp2f(x)
#else
#define EXP2(x) __expf((x) * 0.6931471805599453f)
#endif

__device__ __forceinline__ u16 f2b(float f) {
    uint32_t u = __float_as_uint(f);
    uint32_t r = (u + 0x7fffu + ((u >> 16) & 1u)) >> 16;   // RNE
    return (u16)r;
}

// HW packed f32->bf16 (RNE): lo = bf16(a), hi = bf16(b)
__device__ __forceinline__ uint32_t cvt_pk_bf16(float a, float b) {
    uint32_t r;
    asm("v_cvt_pk_bf16_f32 %0, %1, %2" : "=v"(r) : "v"(a), "v"(b));
    return r;
}

__device__ __forceinline__ void async16(const u16* g, u16* l) {
    __builtin_amdgcn_global_load_lds(
        (const __attribute__((address_space(1))) unsigned int*)g,
        (__attribute__((address_space(3))) unsigned int*)l, 16, 0, 0);
}

// Stage a tile of [rows][cols] bf16 (cols = chunks-of-8 * 8) from global (row
// stride strideE elems) into LDS, 16B per lane, wave-uniform LDS base.
// Logical chunk LC of row r is stored at slot LC ^ ((r >> xshift) & xmask).
__device__ __forceinline__ void stage_lds(const u16* __restrict__ src, size_t strideE,
                                          u16* lds, int wave, int lane,
                                          int log2cpr, int xmask, int xshift,
                                          int reps, int nlanes) {
    const int cmask = (1 << log2cpr) - 1;
    for (int rep = 0; rep < reps; ++rep) {
        int cbase = rep * nlanes + wave * 64;     // wave-uniform
        int ci = cbase + lane;
        int row = ci >> log2cpr;
        int sc = ci & cmask;
        int dchunk = sc ^ ((row >> xshift) & xmask);  // logical chunk landing in slot sc
        const u16* g = src + (size_t)row * strideE + dchunk * 8;
        async16(g, lds + (size_t)cbase * 8);
    }
}

// ------------------------------------------------- fused prep: cast x + 5 transposes
// grid 19456 blocks x 256 thr (see round-6 notes). One-shot 32x32 transpose:
// float4 global reads (16B/lane), ushort4 transposed stores (8B/lane).
__global__ __launch_bounds__(256) void prep(const float* __restrict__ x,
                                            const float* __restrict__ Wq,
                                            const float* __restrict__ Wl,
                                            const float* __restrict__ Wk,
                                            const float* __restrict__ Wv,
                                            const float* __restrict__ Wo,
                                            u16* __restrict__ xb,
                                            u16* __restrict__ WqlT,
                                            u16* __restrict__ WkvT,
                                            u16* __restrict__ WoT) {
    const int t = blockIdx.x, tid = threadIdx.x;
    if (t < 8192) {
        int i = t * 256 + tid;
        float4 v = ((const float4*)x)[i];
        unsigned int lo = (unsigned int)f2b(v.x) | ((unsigned int)f2b(v.y) << 16);
        unsigned int hi = (unsigned int)f2b(v.z) | ((unsigned int)f2b(v.w) << 16);
        ((uint2*)xb)[i] = make_uint2(lo, hi);
        return;
    }
    __shared__ float tile[32][33];
    const float* src; u16* dst; int R, C, tY, tX;
    if (t < 12288)      { int tt = t - 8192;  src = Wq; dst = WqlT;           R = 2048; C = 2048; tY = tt >> 6; tX = tt & 63; }
    else if (t < 13312) { int tt = t - 12288; src = Wl; dst = WqlT + 4194304; R = 2048; C = 512;  tY = tt >> 4; tX = tt & 15; }
    else if (t < 14336) { int tt = t - 13312; int hh = tt >> 6; tt &= 63;
                          src = Wk + hh * 65536; dst = WkvT + hh * 65536;     R = 512;  C = 128;  tY = tt >> 2; tX = tt & 3; }
    else if (t < 15360) { int tt = t - 14336; int hh = tt >> 6; tt &= 63;
                          src = Wv + hh * 65536; dst = WkvT + 1048576 + hh * 65536;
                                                                              R = 512;  C = 128;  tY = tt >> 2; tX = tt & 3; }
    else                { int tt = t - 15360; src = Wo; dst = WoT;            R = 2048; C = 2048; tY = tt >> 6; tX = tt & 63; }
    const int r0 = tY * 32, c0 = tX * 32;
    {
        const int rr = tid >> 3, c4 = tid & 7;
        float4 v4 = *(const float4*)&src[(size_t)(r0 + rr) * C + c0 + c4 * 4];
        tile[rr][c4 * 4 + 0] = v4.x;
        tile[rr][c4 * 4 + 1] = v4.y;
        tile[rr][c4 * 4 + 2] = v4.z;
        tile[rr][c4 * 4 + 3] = v4.w;
    }
    __syncthreads();
    {
        const int rg = tid & 7, cc = tid >> 3;
        ushort4 o4;
        o4.x = f2b(tile[rg * 4 + 0][cc]);
        o4.y = f2b(tile[rg * 4 + 1][cc]);
        o4.z = f2b(tile[rg * 4 + 2][cc]);
        o4.w = f2b(tile[rg * 4 + 3][cc]);
        *(ushort4*)&dst[(size_t)(c0 + cc) * R + r0 + rg * 4] = o4;
    }
}

// ---------------------------------------------------------------- GEMM
// C = A[M][K] @ Bt[N][K]^T + bias. Double-buffered LDS, one barrier/iter.
// BK=32: LDS 32KB -> 5 blocks/CU cap (gemm<3>'s 640-block grid fully
// co-resident, no serialized tail — BK=64's 64KB cap caused a half-machine
// tail phase, measured Occupancy 13%). BK=64 kept only where grid = 2/CU
// exactly (gemm<2>: 512 blocks).
// Chunked bijective XCD swizzle (m204). STORE semantics as before.
template<int STORE, int BK>
__global__ __launch_bounds__(256) void gemm_bt(const u16* __restrict__ A,
                                               const u16* __restrict__ Bt,
                                               const float* __restrict__ bias1,
                                               const float* __restrict__ bias2,
                                               void* __restrict__ C1,
                                               void* __restrict__ C2,
                                               int M, int N, int K) {
    __shared__ __align__(16) u16 As[2][128 * BK];
    __shared__ __align__(16) u16 Bs[2][128 * BK];
    const int tid = threadIdx.x, wave = tid >> 6, lane = tid & 63;
    const int quad = lane >> 4, m16 = lane & 15;
    const int gx = gridDim.x;
    const int nwg = gx * gridDim.y;
    int lin = blockIdx.x + gx * blockIdx.y;
    int xcd = lin & 7, pos = lin >> 3;
    int qq = nwg >> 3, rr2 = nwg & 7;
    int wg = (xcd < rr2) ? xcd * (qq + 1) + pos
                         : rr2 * (qq + 1) + (xcd - rr2) * qq + pos;
    const int m0 = (wg / gx) * 128, n0 = (wg % gx) * 128;
    const int wr = wave >> 1, wc = wave & 1;
    const u16* Ab = A + (size_t)m0 * K;
    const u16* Bb = Bt + (size_t)n0 * K;
    const int KI = K / BK;

    auto stage = [&](const u16* src, u16* buf) {
        if constexpr (BK == 32) stage_lds(src, K, buf, wave, lane, 2, 3, 1, 2, 256);
        else                    stage_lds(src, K, buf, wave, lane, 3, 7, 0, 4, 256);
    };

    stage(Ab, As[0]);
    stage(Bb, Bs[0]);

    f32x4 acc[4][4] = {};
    for (int it = 0; it < KI; ++it) {
        const int cur = it & 1;
        __syncthreads();
        if (it + 1 < KI) {
            stage(Ab + (it + 1) * BK, As[cur ^ 1]);
            stage(Bb + (it + 1) * BK, Bs[cur ^ 1]);
        }
        if constexpr (BK == 32) {
            const int swz = (quad ^ ((m16 >> 1) & 3)) * 8;
            short8 af[4], bfr[4];
            #pragma unroll
            for (int i = 0; i < 4; i++)
                af[i] = *(const short8*)&As[cur][(wr * 64 + i * 16 + m16) * 32 + swz];
            #pragma unroll
            for (int j = 0; j < 4; j++)
                bfr[j] = *(const short8*)&Bs[cur][(wc * 64 + j * 16 + m16) * 32 + swz];
            #pragma unroll
            for (int i = 0; i < 4; i++)
                #pragma unroll
                for (int j = 0; j < 4; j++)
                    acc[i][j] = MFMA16(af[i], bfr[j], acc[i][j], 0, 0, 0);
        } else {
            #pragma unroll
            for (int kk = 0; kk < 2; kk++) {
                const int swz = ((kk * 4 + quad) ^ (m16 & 7)) * 8;
                short8 af[4], bfr[4];
                #pragma unroll
                for (int i = 0; i < 4; i++)
                    af[i] = *(const short8*)&As[cur][(wr * 64 + i * 16 + m16) * 64 + swz];
                #pragma unroll
                for (int j = 0; j < 4; j++)
                    bfr[j] = *(const short8*)&Bs[cur][(wc * 64 + j * 16 + m16) * 64 + swz];
                #pragma unroll
                for (int i = 0; i < 4; i++)
                    #pragma unroll
                    for (int j = 0; j < 4; j++)
                        acc[i][j] = MFMA16(af[i], bfr[j], acc[i][j], 0, 0, 0);
            }
        }
    }
    const bool second = (n0 >= 2048);
    #pragma unroll
    for (int j = 0; j < 4; j++) {
        int n = n0 + wc * 64 + j * 16 + m16;
        float bv;
        if constexpr (STORE == 2) bv = bias1[n];
        else bv = second ? bias2[n - 2048] : bias1[n];
        #pragma unroll
        for (int i = 0; i < 4; i++) {
            int mrow = m0 + wr * 64 + i * 16 + quad * 4;
            if constexpr (STORE == 4) {
                if (second) {
                    int n2 = n - 2048;
                    ushort4 pkv;
                    pkv.x = f2b(acc[i][j][0] + bv);
                    pkv.y = f2b(acc[i][j][1] + bv);
                    pkv.z = f2b(acc[i][j][2] + bv);
                    pkv.w = f2b(acc[i][j][3] + bv);
                    int c = mrow & 2047;
                    c = (c & ~12) | ((c & 4) << 1) | ((c & 8) >> 1);  // sigma: swap bits 2,3
                    *(ushort4*)&((u16*)C2)[((size_t)((m0 >> 11) * 2048 + n2)) * 2048 + c] = pkv;
                    continue;
                }
            }
            #pragma unroll
            for (int r = 0; r < 4; r++) {
                float v = acc[i][j][r] + bv;
                int m = mrow + r;
                if constexpr (STORE == 2)
                    ((float*)C1)[(size_t)m * N + n] = v;
                else if constexpr (STORE == 3) {
                    if (!second) ((u16*)C1)[(size_t)m * 2048 + n] = f2b(v * QSCALE);
                    else         ((u16*)C2)[(size_t)m * 512 + (n - 2048)] = f2b(v);
                } else {  // STORE == 4, first region
                    ((u16*)C1)[(size_t)m * 2048 + n] = f2b(v);
                }
            }
        }
    }
}

// ---------------------------------------------------------------- fused attention
// QBLK=64 / KVBLK=32: 4 waves/block, 16 q-rows/wave; grid (32 bh, 32 q) =
// 1024 blocks = 4 blocks/CU exactly; LDS 32KB (Kt 2x[32][128] + Vt 2x[128][32])
// -> occupancy cap 5/CU, so 16 waves/CU resident (2x round-6's 8): TLP fills
// the QK->softmax->PV dependency bubbles.
// Same verified algebra as round-6: swapped QK^T (lane holds full P-row for
// q=m16), in-register P via cvt_pk + one permlane32_swap per reg pair. The
// k-slot->kv map is swap(bit2,bit3) — identical sigma to gemm<4>'s V scatter
// (sigma only touches bits 2-3, so it is tile-size invariant; re-derived and
// slot-checked for all 4 quads at KVBLK=32).
// V staging swizzle uses (row>>1)&3 (xshift=1): read slot quad^((m16>>1)&3)
// gives 2-way-max bank aliasing (free); row&3 would be a 4-way conflict.
// K/V double-buffered, one barrier/iter, prefetch-after-barrier (round-6
// structure preserved).
// Q,K: bf16 [4096][2048]; Vt: bf16 [4096][2048] sigma-permuted cols; Ob same.
__global__ __launch_bounds__(256, 4) void attn_fused(const u16* __restrict__ Q,
                                                     const u16* __restrict__ Kf,
                                                     const u16* __restrict__ Vt,
                                                     u16* __restrict__ Ob) {
    __shared__ __align__(16) u16 Kt[2][32 * 128];    // [dbuf][32 kv][128 d] (also Q stage)
    __shared__ __align__(16) u16 Vtile[2][128 * 32]; // [dbuf][128 d][32 kv-slots]
    const int tid = threadIdx.x, wave = tid >> 6, lane = tid & 63;
    const int quad = lane >> 4, m16 = lane & 15;
    const int bh = blockIdx.x, b = bh >> 4, h = bh & 15;   // bh fast -> XCD = bh%8
    const int q0 = blockIdx.y * 64;
    const size_t grow = (size_t)b * SEQ;
    const u16* Kbase = Kf + grow * NHID + h * DHEAD;
    const u16* Vbase = Vt + (grow + h * DHEAD) * SEQ;

    // stage Q tile [64][128]: rows 0..31 -> Kt[0], rows 32..63 -> Kt[1]
    const u16* qsrc = Q + (grow + q0) * NHID + h * DHEAD;
    stage_lds(qsrc, NHID, Kt[0], wave, lane, 4, 15, 0, 2, 256);
    stage_lds(qsrc + (size_t)32 * NHID, NHID, Kt[1], wave, lane, 4, 15, 0, 2, 256);
    __syncthreads();
    short8 qf[4];
    {
        const u16* qbuf = Kt[wave >> 1];
        int rbase = (wave & 1) * 16;   // wave's 16 q-rows within the 32-row buffer
        #pragma unroll
        for (int c = 0; c < 4; c++)
            qf[c] = *(const short8*)&qbuf[(rbase + m16) * 128 +
                                          (((c * 4 + quad) ^ m16)) * 8];
    }
    __syncthreads();   // all waves done reading Q before kv tile 0 overwrites Kt[0]

    // issue kv tile 0 into buffer 0
    stage_lds(Kbase, NHID, Kt[0], wave, lane, 4, 15, 0, 2, 256);
    stage_lds(Vbase, SEQ, Vtile[0], wave, lane, 2, 3, 1, 2, 256);

    f32x4 o[8] = {};
    float lsum = 0.f;

    for (int it = 0; it < SEQ / 32; ++it) {
        const int cur = it & 1;
        __syncthreads();   // tile `it` landed (vmcnt drain overlapped w/ prev compute)
        if (it + 1 < SEQ / 32) {   // async prefetch of tile it+1 into other buffer
            stage_lds(Kbase + (size_t)(it + 1) * 32 * NHID, NHID, Kt[cur ^ 1],
                      wave, lane, 4, 15, 0, 2, 256);
            stage_lds(Vbase + (it + 1) * 32, SEQ, Vtile[cur ^ 1],
                      wave, lane, 2, 3, 1, 2, 256);
        }
        const u16* kt = Kt[cur];
        const u16* vt = Vtile[cur];

        // S^T = K Q^T : s[j] holds q col = m16, kv row = j*16+quad*4+r
        f32x4 s[2] = {};
        __builtin_amdgcn_s_setprio(1);
        #pragma unroll
        for (int c = 0; c < 4; c++)
            #pragma unroll
            for (int j = 0; j < 2; j++) {
                short8 kb = *(const short8*)&kt[(j * 16 + m16) * 128 +
                                               (((c * 4 + quad) ^ m16)) * 8];
                s[j] = MFMA16(kb, qf[c], s[j], 0, 0, 0);
            }
        __builtin_amdgcn_s_setprio(0);

        // p = exp2(s); P-row lane-local; pack bf16 pairs
        uint32_t pk0[2], pk1[2];
        {
            float p0 = EXP2(s[0][0]);
            float p1 = EXP2(s[0][1]);
            float p2 = EXP2(s[0][2]);
            float p3 = EXP2(s[0][3]);
            float p4 = EXP2(s[1][0]);
            float p5 = EXP2(s[1][1]);
            float p6 = EXP2(s[1][2]);
            float p7 = EXP2(s[1][3]);
            lsum += ((p0 + p1) + (p2 + p3)) + ((p4 + p5) + (p6 + p7));
            pk0[0] = cvt_pk_bf16(p0, p1);
            pk0[1] = cvt_pk_bf16(p2, p3);
            pk1[0] = cvt_pk_bf16(p4, p5);
            pk1[1] = cvt_pk_bf16(p6, p7);
        }

        // O += P @ V. A-frag via one permlane32_swap per reg pair; k-slot
        // order = swap(bit2,bit3) = sigma baked into the V layout.
        __builtin_amdgcn_s_setprio(1);
        short8 pa;
        {
            union { uint32_t u[4]; short8 s8; } pu;
#if __has_builtin(__builtin_amdgcn_permlane32_swap)
            auto r0 = __builtin_amdgcn_permlane32_swap(pk0[0], pk1[0], false, false);
            auto r1 = __builtin_amdgcn_permlane32_swap(pk0[1], pk1[1], false, false);
            pu.u[0] = r0[0]; pu.u[1] = r1[0]; pu.u[2] = r0[1]; pu.u[3] = r1[1];
#else
            uint32_t sl0 = __shfl_xor(pk0[0], 32), sl1 = __shfl_xor(pk0[1], 32);
            uint32_t sh0 = __shfl_xor(pk1[0], 32), sh1 = __shfl_xor(pk1[1], 32);
            const bool low = lane < 32;
            pu.u[0] = low ? pk0[0] : sh0;
            pu.u[1] = low ? pk0[1] : sh1;
            pu.u[2] = low ? sl0 : pk1[0];
            pu.u[3] = low ? sl1 : pk1[1];
#endif
            pa = pu.s8;
        }
        #pragma unroll
        for (int jd = 0; jd < 8; jd++) {
            short8 vb = *(const short8*)&vt[(jd * 16 + m16) * 32 +
                                           ((quad ^ ((m16 >> 1) & 3))) * 8];
            o[jd] = MFMA16(pa, vb, o[jd], 0, 0, 0);
        }
        __builtin_amdgcn_s_setprio(0);
    }

    // lane holds partial row-sum for q = m16 (its quad's kv slice);
    // reduce across quads, redistribute to o-layout rows via shfl.
    {
        float v = lsum;
        v += __shfl_xor(v, 16);
        v += __shfl_xor(v, 32);
        lsum = v;
    }
    float inv[4];
    #pragma unroll
    for (int r = 0; r < 4; r++)
        inv[r] = 1.f / __shfl(lsum, quad * 4 + r);
    #pragma unroll
    for (int jd = 0; jd < 8; jd++)
        #pragma unroll
        for (int r = 0; r < 4; r++) {
            int t = q0 + wave * 16 + quad * 4 + r;
            int d = jd * 16 + m16;
            Ob[(grow + t) * NHID + h * DHEAD + d] = f2b(o[jd][r] * inv[r]);
        }
}

// ---------------------------------------------------------------- launch
extern "C" void kernel_launch(void* const* d_in, const int* in_sizes, int n_in,
                              void* d_out, int out_size, void* d_ws, size_t ws_size,
                              hipStream_t stream) {
    const float* x  = (const float*)d_in[0];
    const float* Wq = (const float*)d_in[1];
    const float* bq = (const float*)d_in[2];
    const float* Wl = (const float*)d_in[3];
    const float* bl = (const float*)d_in[4];
    const float* Wk = (const float*)d_in[5];
    const float* bk = (const float*)d_in[6];
    const float* Wv = (const float*)d_in[7];
    const float* bv = (const float*)d_in[8];
    const float* Wo = (const float*)d_in[9];
    const float* bo = (const float*)d_in[10];
    float* out = (float*)d_out;

    u16* w = (u16*)d_ws;
    u16* xb    = w;                   // 8388608 elems (16 MB)
    u16* WqlT  = xb    + 8388608;     // [2560][2048] = 5242880 (10.5 MB)
    u16* WkvT  = WqlT  + 5242880;     // [4096][512]  = 2097152 (4 MB)
    u16* WoT   = WkvT  + 2097152;     // [2048][2048] = 4194304 (8 MB)
    u16* qb    = WoT   + 4194304;     // 8388608 (16 MB)
    u16* kb    = qb    + 8388608;     // 8388608 (16 MB)
    u16* vt    = kb    + 8388608;     // 8388608 (16 MB, transposed+sigma-permuted V)
    u16* lat   = vt    + 8388608;     // [4096][512] = 2097152 (4 MB)
    u16* attnb = xb;                  // alias: xb dead after QL GEMM
    // total 90 MB

    prep<<<19456, 256, 0, stream>>>(x, Wq, Wl, Wk, Wv, Wo, xb, WqlT, WkvT, WoT);

    // fused Q + latent projection: [4096][2048] x [2560][2048]^T
    // BK=32: 32KB LDS -> all 640 blocks co-resident (no 2-block/CU tail)
    gemm_bt<3, 32><<<dim3(20, 32), 256, 0, stream>>>(xb, WqlT, bq, bl, qb, lat,
                                                     NROWS, 2560, 2048);
    // fused K + V back-projection: [4096][512] x [4096][512]^T (BK=32)
    gemm_bt<4, 32><<<dim3(32, 32), 256, 0, stream>>>(lat, WkvT, bk, bv, kb, vt,
                                                     NROWS, 4096, 512);

    // grid (bh, q64): XCD = bh%8; 1024 blocks = 4/CU
    attn_fused<<<dim3(32, 32), 256, 0, stream>>>(qb, kb, vt, attnb);

    // output projection (BK=64: 512 blocks = 2/CU exact fit, fewer drains)
    gemm_bt<2, 64><<<dim3(16, 32), 256, 0, stream>>>(attnb, WoT, bo, nullptr, out, nullptr,
                                                     NROWS, 2048, 2048);
}

// Round 10
// 324.129 us; speedup vs baseline: 1.1946x; 1.0128x over previous
//
#include <hip/hip_runtime.h>
#include <hip/hip_bf16.h>
#include <cstdint>

#define SEQ     2048
#define NHID    2048
#define NLAT    512
#define NHEAD   16
#define DHEAD   128
#define NBATCH  2
#define NROWS   (NBATCH*SEQ)   // 4096

typedef unsigned short u16;
typedef __attribute__((ext_vector_type(8))) short short8;
typedef __attribute__((ext_vector_type(4))) float f32x4;

#define MFMA16 __builtin_amdgcn_mfma_f32_16x16x32_bf16

// 1/sqrt(128) * log2(e): folded into the Q projection so attn softmax is a raw exp2
#define QSCALE 0.12751743f

#if __has_builtin(__builtin_amdgcn_exp2f)
#define EXP2(x) __builtin_amdgcn_exp2f(x)
#else
#define EXP2(x) __expf((x) * 0.6931471805599453f)
#endif

__device__ __forceinline__ u16 f2b(float f) {
    uint32_t u = __float_as_uint(f);
    uint32_t r = (u + 0x7fffu + ((u >> 16) & 1u)) >> 16;   // RNE
    return (u16)r;
}

// HW packed f32->bf16 (RNE): lo = bf16(a), hi = bf16(b)
__device__ __forceinline__ uint32_t cvt_pk_bf16(float a, float b) {
    uint32_t r;
    asm("v_cvt_pk_bf16_f32 %0, %1, %2" : "=v"(r) : "v"(a), "v"(b));
    return r;
}

__device__ __forceinline__ void async16(const u16* g, u16* l) {
    __builtin_amdgcn_global_load_lds(
        (const __attribute__((address_space(1))) unsigned int*)g,
        (__attribute__((address_space(3))) unsigned int*)l, 16, 0, 0);
}

// Stage a tile of [rows][cols] bf16 (cols = chunks-of-8 * 8) from global (row
// stride strideE elems) into LDS, 16B per lane, wave-uniform LDS base.
// Logical chunk LC of row r is stored at slot LC ^ ((r >> xshift) & xmask).
__device__ __forceinline__ void stage_lds(const u16* __restrict__ src, size_t strideE,
                                          u16* lds, int wave, int lane,
                                          int log2cpr, int xmask, int xshift,
                                          int reps, int nlanes) {
    const int cmask = (1 << log2cpr) - 1;
    for (int rep = 0; rep < reps; ++rep) {
        int cbase = rep * nlanes + wave * 64;     // wave-uniform
        int ci = cbase + lane;
        int row = ci >> log2cpr;
        int sc = ci & cmask;
        int dchunk = sc ^ ((row >> xshift) & xmask);  // logical chunk landing in slot sc
        const u16* g = src + (size_t)row * strideE + dchunk * 8;
        async16(g, lds + (size_t)cbase * 8);
    }
}

// ------------------------------------------------- fused prep: cast x + 5 transposes
// grid 19456 blocks x 256 thr (see round-6 notes). One-shot 32x32 transpose:
// float4 global reads (16B/lane), ushort4 transposed stores (8B/lane).
__global__ __launch_bounds__(256) void prep(const float* __restrict__ x,
                                            const float* __restrict__ Wq,
                                            const float* __restrict__ Wl,
                                            const float* __restrict__ Wk,
                                            const float* __restrict__ Wv,
                                            const float* __restrict__ Wo,
                                            u16* __restrict__ xb,
                                            u16* __restrict__ WqlT,
                                            u16* __restrict__ WkvT,
                                            u16* __restrict__ WoT) {
    const int t = blockIdx.x, tid = threadIdx.x;
    if (t < 8192) {
        int i = t * 256 + tid;
        float4 v = ((const float4*)x)[i];
        unsigned int lo = (unsigned int)f2b(v.x) | ((unsigned int)f2b(v.y) << 16);
        unsigned int hi = (unsigned int)f2b(v.z) | ((unsigned int)f2b(v.w) << 16);
        ((uint2*)xb)[i] = make_uint2(lo, hi);
        return;
    }
    __shared__ float tile[32][33];
    const float* src; u16* dst; int R, C, tY, tX;
    if (t < 12288)      { int tt = t - 8192;  src = Wq; dst = WqlT;           R = 2048; C = 2048; tY = tt >> 6; tX = tt & 63; }
    else if (t < 13312) { int tt = t - 12288; src = Wl; dst = WqlT + 4194304; R = 2048; C = 512;  tY = tt >> 4; tX = tt & 15; }
    else if (t < 14336) { int tt = t - 13312; int hh = tt >> 6; tt &= 63;
                          src = Wk + hh * 65536; dst = WkvT + hh * 65536;     R = 512;  C = 128;  tY = tt >> 2; tX = tt & 3; }
    else if (t < 15360) { int tt = t - 14336; int hh = tt >> 6; tt &= 63;
                          src = Wv + hh * 65536; dst = WkvT + 1048576 + hh * 65536;
                                                                              R = 512;  C = 128;  tY = tt >> 2; tX = tt & 3; }
    else                { int tt = t - 15360; src = Wo; dst = WoT;            R = 2048; C = 2048; tY = tt >> 6; tX = tt & 63; }
    const int r0 = tY * 32, c0 = tX * 32;
    {
        const int rr = tid >> 3, c4 = tid & 7;
        float4 v4 = *(const float4*)&src[(size_t)(r0 + rr) * C + c0 + c4 * 4];
        tile[rr][c4 * 4 + 0] = v4.x;
        tile[rr][c4 * 4 + 1] = v4.y;
        tile[rr][c4 * 4 + 2] = v4.z;
        tile[rr][c4 * 4 + 3] = v4.w;
    }
    __syncthreads();
    {
        const int rg = tid & 7, cc = tid >> 3;
        ushort4 o4;
        o4.x = f2b(tile[rg * 4 + 0][cc]);
        o4.y = f2b(tile[rg * 4 + 1][cc]);
        o4.z = f2b(tile[rg * 4 + 2][cc]);
        o4.w = f2b(tile[rg * 4 + 3][cc]);
        *(ushort4*)&dst[(size_t)(c0 + cc) * R + r0 + rg * 4] = o4;
    }
}

// ---------------------------------------------------------------- GEMM
// C = A[M][K] @ Bt[N][K]^T + bias. Double-buffered LDS, one barrier/iter.
// BK=32 (32KB LDS, 5 blocks/CU cap) except gemm<2> at BK=64 (512 blocks =
// 2/CU exact fit, half the barrier drains). Chunked bijective XCD swizzle.
// STORE 2: f32 row-major to C1 (bias1)
// STORE 3: n<2048 -> bf16 (bias1 then *QSCALE) C1[m][n]; n>=2048 -> bf16
//          C2[m][n-2048] (stride 512, bias2)
// STORE 4: n<2048 -> bf16 C1[m][n] (kb); n>=2048 -> vt via OPERAND-SWAPPED
//          MFMA: acc = mfma(bfr, af) gives the transposed D-tile (row=n,
//          col=m) because A- and B-frags share the same lane layout. The
//          epilogue then stores vt[(m>>11)*2048+n2][sigma(m&2047)] with m on
//          the lane axis -> 16-lane-contiguous 32B runs instead of 8B
//          scatters to lines 4KB apart (the round-9 51MB write-amp).
//          sigma (swap bits 2,3) reduces to a per-lane constant remap of m16.
template<int STORE, int BK>
__global__ __launch_bounds__(256) void gemm_bt(const u16* __restrict__ A,
                                               const u16* __restrict__ Bt,
                                               const float* __restrict__ bias1,
                                               const float* __restrict__ bias2,
                                               void* __restrict__ C1,
                                               void* __restrict__ C2,
                                               int M, int N, int K) {
    __shared__ __align__(16) u16 As[2][128 * BK];
    __shared__ __align__(16) u16 Bs[2][128 * BK];
    const int tid = threadIdx.x, wave = tid >> 6, lane = tid & 63;
    const int quad = lane >> 4, m16 = lane & 15;
    const int gx = gridDim.x;
    const int nwg = gx * gridDim.y;
    int lin = blockIdx.x + gx * blockIdx.y;
    int xcd = lin & 7, pos = lin >> 3;
    int qq = nwg >> 3, rr2 = nwg & 7;
    int wg = (xcd < rr2) ? xcd * (qq + 1) + pos
                         : rr2 * (qq + 1) + (xcd - rr2) * qq + pos;
    const int m0 = (wg / gx) * 128, n0 = (wg % gx) * 128;
    const int wr = wave >> 1, wc = wave & 1;
    const u16* Ab = A + (size_t)m0 * K;
    const u16* Bb = Bt + (size_t)n0 * K;
    const int KI = K / BK;
    const bool second = (n0 >= 2048);   // block-uniform (2048 % 128 == 0)

    auto stage = [&](const u16* src, u16* buf) {
        if constexpr (BK == 32) stage_lds(src, K, buf, wave, lane, 2, 3, 1, 2, 256);
        else                    stage_lds(src, K, buf, wave, lane, 3, 7, 0, 4, 256);
    };

    stage(Ab, As[0]);
    stage(Bb, Bs[0]);

    f32x4 acc[4][4] = {};
    for (int it = 0; it < KI; ++it) {
        const int cur = it & 1;
        __syncthreads();
        if (it + 1 < KI) {
            stage(Ab + (it + 1) * BK, As[cur ^ 1]);
            stage(Bb + (it + 1) * BK, Bs[cur ^ 1]);
        }
        if constexpr (BK == 32) {
            const int swz = (quad ^ ((m16 >> 1) & 3)) * 8;
            short8 af[4], bfr[4];
            #pragma unroll
            for (int i = 0; i < 4; i++)
                af[i] = *(const short8*)&As[cur][(wr * 64 + i * 16 + m16) * 32 + swz];
            #pragma unroll
            for (int j = 0; j < 4; j++)
                bfr[j] = *(const short8*)&Bs[cur][(wc * 64 + j * 16 + m16) * 32 + swz];
            if constexpr (STORE == 4) {
                if (second) {   // swapped operands -> transposed D (row=n, col=m)
                    #pragma unroll
                    for (int i = 0; i < 4; i++)
                        #pragma unroll
                        for (int j = 0; j < 4; j++)
                            acc[i][j] = MFMA16(bfr[j], af[i], acc[i][j], 0, 0, 0);
                } else {
                    #pragma unroll
                    for (int i = 0; i < 4; i++)
                        #pragma unroll
                        for (int j = 0; j < 4; j++)
                            acc[i][j] = MFMA16(af[i], bfr[j], acc[i][j], 0, 0, 0);
                }
            } else {
                #pragma unroll
                for (int i = 0; i < 4; i++)
                    #pragma unroll
                    for (int j = 0; j < 4; j++)
                        acc[i][j] = MFMA16(af[i], bfr[j], acc[i][j], 0, 0, 0);
            }
        } else {
            #pragma unroll
            for (int kk = 0; kk < 2; kk++) {
                const int swz = ((kk * 4 + quad) ^ (m16 & 7)) * 8;
                short8 af[4], bfr[4];
                #pragma unroll
                for (int i = 0; i < 4; i++)
                    af[i] = *(const short8*)&As[cur][(wr * 64 + i * 16 + m16) * 64 + swz];
                #pragma unroll
                for (int j = 0; j < 4; j++)
                    bfr[j] = *(const short8*)&Bs[cur][(wc * 64 + j * 16 + m16) * 64 + swz];
                #pragma unroll
                for (int i = 0; i < 4; i++)
                    #pragma unroll
                    for (int j = 0; j < 4; j++)
                        acc[i][j] = MFMA16(af[i], bfr[j], acc[i][j], 0, 0, 0);
            }
        }
    }

    if constexpr (STORE == 4) {
        if (second) {
            // transposed-acc epilogue: acc[i][j][r] is (n = n0-2048 + wc*64 +
            // j*16 + quad*4 + r, m = m0 + wr*64 + i*16 + m16).
            // vt row = (m0>>11)*2048 + n; col = sigma(m&2047); sigma hits only
            // bits 2,3 = bits of m16 -> per-lane constant m16s.
            const int m16s = (m16 & 3) | ((m16 & 4) << 1) | ((m16 & 8) >> 1);
            const int n2b = (n0 - 2048) + wc * 64 + quad * 4;
            const size_t rowbase = (size_t)(m0 >> 11) * 2048;
            const int colbase = (m0 & 2047) + wr * 64 + m16s;
            #pragma unroll
            for (int j = 0; j < 4; j++) {
                #pragma unroll
                for (int r = 0; r < 4; r++) {
                    const int n2 = n2b + j * 16 + r;
                    const float bv = bias2[n2];
                    #pragma unroll
                    for (int i = 0; i < 4; i++)
                        ((u16*)C2)[(rowbase + n2) * 2048 + colbase + i * 16] =
                            f2b(acc[i][j][r] + bv);
                }
            }
            return;
        }
    }

    #pragma unroll
    for (int j = 0; j < 4; j++) {
        int n = n0 + wc * 64 + j * 16 + m16;
        float bv;
        if constexpr (STORE == 2) bv = bias1[n];
        else bv = second ? bias2[n - 2048] : bias1[n];
        #pragma unroll
        for (int i = 0; i < 4; i++) {
            int mrow = m0 + wr * 64 + i * 16 + quad * 4;
            #pragma unroll
            for (int r = 0; r < 4; r++) {
                float v = acc[i][j][r] + bv;
                int m = mrow + r;
                if constexpr (STORE == 2)
                    ((float*)C1)[(size_t)m * N + n] = v;
                else if constexpr (STORE == 3) {
                    if (!second) ((u16*)C1)[(size_t)m * 2048 + n] = f2b(v * QSCALE);
                    else         ((u16*)C2)[(size_t)m * 512 + (n - 2048)] = f2b(v);
                } else {  // STORE == 4, first region (kb)
                    ((u16*)C1)[(size_t)m * 2048 + n] = f2b(v);
                }
            }
        }
    }
}

// ---------------------------------------------------------------- fused attention
// (round-6 version restored — best measured 75.8us. Round-9's QBLK=64/KVBLK=32
// shrink raised occupancy but tripled barrier frequency per MFMA: regression.)
// 4 waves/block, 32 q-rows/wave (128 q/block). K/V tiles double-buffered (64KB
// LDS, 2 blocks/CU): per iter, barrier FIRST (drains tile it), then issue
// async prefetch of tile it+1 into the other buffer, then compute on tile it.
// Grid is (bh, q): XCD = bh%8, so each XCD's L2 holds 4 (b,h)-pairs' KV (4MB)
// -> KV re-reads across the 16 q-blocks are L2 hits instead of HBM.
// Swapped QK^T: S^T = mfma(A=K, B=Q) so each lane holds a full P-row
// (q = i*16+m16, 16 kv values per j). P never touches LDS: 16 cvt_pk +
// 8 permlane32_swap per tile build the PV A-frags in registers. The implied
// kv k-slot permutation (swap bits 2<->3 within each 64-block) is baked into
// the V layout by gemm_bt<4>'s sigma'd store, so V staging/reads are unchanged.
// No-max softmax (|s'| << 115 in exp2 domain); Q pre-scaled by 1/sqrt(128)*log2e.
// Row-sum: one scalar/lane/half, reduced across quads after the kv loop.
// Q,K: bf16 [4096][2048] (row = b*2048+t, col = h*128+d)
// Vt:  bf16 [4096][2048] (row = b*2048+h*128+d, col = sigma-permuted t)
// Ob:  bf16 [4096][2048]
__global__ __launch_bounds__(256, 2) void attn_fused(const u16* __restrict__ Q,
                                                     const u16* __restrict__ Kf,
                                                     const u16* __restrict__ Vt,
                                                     u16* __restrict__ Ob) {
    __shared__ __align__(16) u16 Kt[2][64 * 128];     // [dbuf][64 kv][128 d] (also Q stage)
    __shared__ __align__(16) u16 Vtile[2][128 * 64];  // [dbuf][128 d][64 kv-slots]
    const int tid = threadIdx.x, wave = tid >> 6, lane = tid & 63;
    const int quad = lane >> 4, m16 = lane & 15;
    const int bh = blockIdx.x, b = bh >> 4, h = bh & 15;   // bh fast -> XCD = bh%8
    const int q0 = blockIdx.y * 128;
    const size_t grow = (size_t)b * SEQ;
    const u16* Kbase = Kf + grow * NHID + h * DHEAD;
    const u16* Vbase = Vt + (grow + h * DHEAD) * SEQ;

    // stage Q tile [128][128]: rows 0..63 -> Kt[0], rows 64..127 -> Kt[1]
    const u16* qsrc = Q + (grow + q0) * NHID + h * DHEAD;
    stage_lds(qsrc, NHID, Kt[0], wave, lane, 4, 15, 0, 4, 256);
    stage_lds(qsrc + (size_t)64 * NHID, NHID, Kt[1], wave, lane, 4, 15, 0, 4, 256);
    __syncthreads();
    short8 qf[2][4];
    {
        const u16* qbuf = Kt[wave >> 1];
        int rbase = (wave & 1) * 32;
        #pragma unroll
        for (int i = 0; i < 2; i++)
            #pragma unroll
            for (int c = 0; c < 4; c++)
                qf[i][c] = *(const short8*)&qbuf[(rbase + i * 16 + m16) * 128 +
                                                (((c * 4 + quad) ^ m16)) * 8];
    }
    __syncthreads();   // all waves done reading Q before kv tile 0 overwrites Kt[0]

    // issue kv tile 0 into buffer 0
    stage_lds(Kbase, NHID, Kt[0], wave, lane, 4, 15, 0, 4, 256);
    stage_lds(Vbase, SEQ, Vtile[0], wave, lane, 3, 7, 0, 4, 256);

    f32x4 o[2][8] = {};
    float lsum[2] = {};

    for (int it = 0; it < SEQ / 64; ++it) {
        const int cur = it & 1;
        __syncthreads();   // tile `it` landed (vmcnt drain overlapped w/ prev compute)
        if (it + 1 < SEQ / 64) {   // async prefetch of tile it+1 into other buffer
            stage_lds(Kbase + (size_t)(it + 1) * 64 * NHID, NHID, Kt[cur ^ 1],
                      wave, lane, 4, 15, 0, 4, 256);
            stage_lds(Vbase + (it + 1) * 64, SEQ, Vtile[cur ^ 1],
                      wave, lane, 3, 7, 0, 4, 256);
        }
        const u16* kt = Kt[cur];
        const u16* vt = Vtile[cur];

        // S^T = K Q^T : s[i][j] holds q col = i*16+m16, kv row = j*16+quad*4+r
        f32x4 s[2][4] = {};
        __builtin_amdgcn_s_setprio(1);
        #pragma unroll
        for (int c = 0; c < 4; c++)
            #pragma unroll
            for (int j = 0; j < 4; j++) {
                short8 kb = *(const short8*)&kt[(j * 16 + m16) * 128 +
                                               (((c * 4 + quad) ^ m16)) * 8];
                s[0][j] = MFMA16(kb, qf[0][c], s[0][j], 0, 0, 0);
                s[1][j] = MFMA16(kb, qf[1][c], s[1][j], 0, 0, 0);
            }
        __builtin_amdgcn_s_setprio(0);

        // p = exp2(s) (scale pre-folded into Q); full P-row is lane-local.
        // Pack to bf16 pairs: pk[i][j][w] = (p[4j+2w], p[4j+2w+1]).
        uint32_t pk[2][4][2];
        #pragma unroll
        for (int i = 0; i < 2; i++) {
            float rs = 0.f;
            #pragma unroll
            for (int j = 0; j < 4; j++) {
                float p0 = EXP2(s[i][j][0]);
                float p1 = EXP2(s[i][j][1]);
                float p2 = EXP2(s[i][j][2]);
                float p3 = EXP2(s[i][j][3]);
                rs += (p0 + p1) + (p2 + p3);
                pk[i][j][0] = cvt_pk_bf16(p0, p1);
                pk[i][j][1] = cvt_pk_bf16(p2, p3);
            }
            lsum[i] += rs;
        }

        // O += P @ V. A-frag built in-register: one permlane32_swap per reg pair
        // gives pa = [A'w0, A'w1, B'w0, B'w1] uniformly for all lanes (k-slot
        // order matches the sigma-permuted V layout).
        __builtin_amdgcn_s_setprio(1);
        #pragma unroll
        for (int c2 = 0; c2 < 2; c2++) {
            short8 pa[2];
            #pragma unroll
            for (int i = 0; i < 2; i++) {
                union { uint32_t u[4]; short8 s8; } pu;
#if __has_builtin(__builtin_amdgcn_permlane32_swap)
                auto r0 = __builtin_amdgcn_permlane32_swap(pk[i][2 * c2][0],
                                                           pk[i][2 * c2 + 1][0],
                                                           false, false);
                auto r1 = __builtin_amdgcn_permlane32_swap(pk[i][2 * c2][1],
                                                           pk[i][2 * c2 + 1][1],
                                                           false, false);
                pu.u[0] = r0[0]; pu.u[1] = r1[0]; pu.u[2] = r0[1]; pu.u[3] = r1[1];
#else
                uint32_t jl0 = pk[i][2 * c2][0],     jl1 = pk[i][2 * c2][1];
                uint32_t jh0 = pk[i][2 * c2 + 1][0], jh1 = pk[i][2 * c2 + 1][1];
                uint32_t sl0 = __shfl_xor(jl0, 32), sl1 = __shfl_xor(jl1, 32);
                uint32_t sh0 = __shfl_xor(jh0, 32), sh1 = __shfl_xor(jh1, 32);
                const bool low = lane < 32;
                pu.u[0] = low ? jl0 : sh0;
                pu.u[1] = low ? jl1 : sh1;
                pu.u[2] = low ? sl0 : jh0;
                pu.u[3] = low ? sl1 : jh1;
#endif
                pa[i] = pu.s8;
            }
            #pragma unroll
            for (int jd = 0; jd < 8; jd++) {
                short8 vb = *(const short8*)&vt[(jd * 16 + m16) * 64 +
                                               (((c2 * 4 + quad) ^ (m16 & 7))) * 8];
                o[0][jd] = MFMA16(pa[0], vb, o[0][jd], 0, 0, 0);
                o[1][jd] = MFMA16(pa[1], vb, o[1][jd], 0, 0, 0);
            }
        }
        __builtin_amdgcn_s_setprio(0);
    }

    // lane holds partial row-sum for q = i*16+m16; reduce across quads (lanes
    // +-16, +-32), then redistribute to the o-layout rows (quad*4+r) via shfl.
    #pragma unroll
    for (int i = 0; i < 2; i++) {
        float v = lsum[i];
        v += __shfl_xor(v, 16);
        v += __shfl_xor(v, 32);
        lsum[i] = v;
    }
    #pragma unroll
    for (int i = 0; i < 2; i++) {
        float inv[4];
        #pragma unroll
        for (int r = 0; r < 4; r++)
            inv[r] = 1.f / __shfl(lsum[i], quad * 4 + r);
        #pragma unroll
        for (int jd = 0; jd < 8; jd++)
            #pragma unroll
            for (int r = 0; r < 4; r++) {
                int t = q0 + wave * 32 + i * 16 + quad * 4 + r;
                int d = jd * 16 + m16;
                Ob[(grow + t) * NHID + h * DHEAD + d] = f2b(o[i][jd][r] * inv[r]);
            }
    }
}

// ---------------------------------------------------------------- launch
extern "C" void kernel_launch(void* const* d_in, const int* in_sizes, int n_in,
                              void* d_out, int out_size, void* d_ws, size_t ws_size,
                              hipStream_t stream) {
    const float* x  = (const float*)d_in[0];
    const float* Wq = (const float*)d_in[1];
    const float* bq = (const float*)d_in[2];
    const float* Wl = (const float*)d_in[3];
    const float* bl = (const float*)d_in[4];
    const float* Wk = (const float*)d_in[5];
    const float* bk = (const float*)d_in[6];
    const float* Wv = (const float*)d_in[7];
    const float* bv = (const float*)d_in[8];
    const float* Wo = (const float*)d_in[9];
    const float* bo = (const float*)d_in[10];
    float* out = (float*)d_out;

    u16* w = (u16*)d_ws;
    u16* xb    = w;                   // 8388608 elems (16 MB)
    u16* WqlT  = xb    + 8388608;     // [2560][2048] = 5242880 (10.5 MB)
    u16* WkvT  = WqlT  + 5242880;     // [4096][512]  = 2097152 (4 MB)
    u16* WoT   = WkvT  + 2097152;     // [2048][2048] = 4194304 (8 MB)
    u16* qb    = WoT   + 4194304;     // 8388608 (16 MB)
    u16* kb    = qb    + 8388608;     // 8388608 (16 MB)
    u16* vt    = kb    + 8388608;     // 8388608 (16 MB, transposed+sigma-permuted V)
    u16* lat   = vt    + 8388608;     // [4096][512] = 2097152 (4 MB)
    u16* attnb = xb;                  // alias: xb dead after QL GEMM
    // total 90 MB

    prep<<<19456, 256, 0, stream>>>(x, Wq, Wl, Wk, Wv, Wo, xb, WqlT, WkvT, WoT);

    // fused Q + latent projection: [4096][2048] x [2560][2048]^T (BK=32)
    gemm_bt<3, 32><<<dim3(20, 32), 256, 0, stream>>>(xb, WqlT, bq, bl, qb, lat,
                                                     NROWS, 2560, 2048);
    // fused K + V back-projection: [4096][512] x [4096][512]^T (BK=32;
    // vt region uses operand-swapped MFMA -> coalesced transposed stores)
    gemm_bt<4, 32><<<dim3(32, 32), 256, 0, stream>>>(lat, WkvT, bk, bv, kb, vt,
                                                     NROWS, 4096, 512);

    // grid (bh, q): XCD = bh%8 -> per-XCD L2 holds 4 (b,h)-pairs' KV (4MB)
    attn_fused<<<dim3(32, 16), 256, 0, stream>>>(qb, kb, vt, attnb);

    // output projection (BK=64: 512 blocks = 2/CU exact fit, fewer drains)
    gemm_bt<2, 64><<<dim3(16, 32), 256, 0, stream>>>(attnb, WoT, bo, nullptr, out, nullptr,
                                                     NROWS, 2048, 2048);
}